// Round 8
// baseline (556.187 us; speedup 1.0000x reference)
//
#include <hip/hip_runtime.h>
#include <hip/hip_bf16.h>
#include <hip/hip_fp16.h>

// Problem constants (from reference)
#define NN 50000
#define NE 800000
#define ET (NE + NN)          // edges + self loops = 850000
#define FIN 256
#define HC 192                // H*C = 3*64
#define NHEAD 3
#define CDIM 64
#define MAXDEG 128            // fast-path cap; Poisson(17) max over 50K nodes ~45
#define MLW 384               // hml row width (mu 0..191 | lv 192..383)

typedef short short8 __attribute__((ext_vector_type(8)));
typedef float f32x4 __attribute__((ext_vector_type(4)));

// ---------------------------------------------------------------------------
// CSR build: histogram -> scan -> scatter (graph shared by all 3 GAT layers)
// ---------------------------------------------------------------------------
__global__ __launch_bounds__(256) void hist_kernel(const int* __restrict__ ei,
                                                   int* __restrict__ cnt) {
    int e = blockIdx.x * 256 + threadIdx.x;
    if (e >= ET) return;
    int dst = (e < NE) ? ei[NE + e] : (e - NE);
    atomicAdd(&cnt[dst], 1);
}

#define SCAN_BLK 1024
__global__ __launch_bounds__(SCAN_BLK) void scan1_kernel(const int* __restrict__ cnt,
                                                         int* __restrict__ row_ptr,
                                                         int* __restrict__ partials) {
    __shared__ int sm[SCAN_BLK];
    int t = threadIdx.x;
    int g = blockIdx.x * SCAN_BLK + t;
    int v = (g < NN) ? cnt[g] : 0;
    sm[t] = v;
    __syncthreads();
    for (int off = 1; off < SCAN_BLK; off <<= 1) {
        int u = (t >= off) ? sm[t - off] : 0;
        __syncthreads();
        sm[t] += u;
        __syncthreads();
    }
    if (g < NN) row_ptr[g + 1] = sm[t];
    if (t == SCAN_BLK - 1) partials[blockIdx.x] = sm[t];
}

__global__ __launch_bounds__(64) void scan2_kernel(int* __restrict__ partials, int nb) {
    int t = threadIdx.x;
    int v = (t < nb) ? partials[t] : 0;
    int x = v;
    for (int off = 1; off < 64; off <<= 1) {
        int y = __shfl_up(x, off);
        if (t >= off) x += y;
    }
    if (t < nb) partials[t] = x - v;
}

// also zeroes cnt so scatter can reuse it (saves a memset dispatch)
__global__ __launch_bounds__(SCAN_BLK) void scan3_kernel(int* __restrict__ row_ptr,
                                                         const int* __restrict__ partials,
                                                         int* __restrict__ cnt) {
    int g = blockIdx.x * SCAN_BLK + threadIdx.x;
    if (g < NN) {
        row_ptr[g + 1] += partials[blockIdx.x];
        cnt[g] = 0;
    }
    if (g == 0) row_ptr[0] = 0;
}

__global__ __launch_bounds__(256) void scatter_kernel(const int* __restrict__ ei,
                                                      int* __restrict__ cnt,
                                                      const int* __restrict__ row_ptr,
                                                      int* __restrict__ csr_src) {
    int e = blockIdx.x * 256 + threadIdx.x;
    if (e >= ET) return;
    int src, dst;
    if (e < NE) { src = ei[e]; dst = ei[NE + e]; }
    else        { src = e - NE; dst = e - NE; }
    int pos = atomicAdd(&cnt[dst], 1);
    csr_src[row_ptr[dst] + pos] = src;
}

// ---------------------------------------------------------------------------
// fp32 -> bf16 split helpers
// ---------------------------------------------------------------------------
__device__ __forceinline__ unsigned short f2bf(float f) {
    unsigned int u = __float_as_uint(f);
    unsigned int r = (u + 0x7FFFu + ((u >> 16) & 1u)) >> 16;   // RNE
    return (unsigned short)r;
}
__device__ __forceinline__ float bf2f(unsigned short h) {
    return __uint_as_float(((unsigned int)h) << 16);
}

// ---------------------------------------------------------------------------
// Precompute bf16 hi/lo splits (removes all f2bf VALU from GEMM K-loops).
// ---------------------------------------------------------------------------
__global__ __launch_bounds__(256) void split_x_kernel(const float* __restrict__ in,
                                                      unsigned short* __restrict__ hi,
                                                      unsigned short* __restrict__ lo,
                                                      int nquad) {
    int i = blockIdx.x * 256 + threadIdx.x;
    if (i >= nquad) return;
    float4 v = reinterpret_cast<const float4*>(in)[i];
    unsigned short h0 = f2bf(v.x), h1 = f2bf(v.y), h2 = f2bf(v.z), h3 = f2bf(v.w);
    unsigned short g0 = f2bf(v.x - bf2f(h0)), g1 = f2bf(v.y - bf2f(h1));
    unsigned short g2 = f2bf(v.z - bf2f(h2)), g3 = f2bf(v.w - bf2f(h3));
    reinterpret_cast<uint2*>(hi)[i] =
        make_uint2((unsigned)h0 | ((unsigned)h1 << 16), (unsigned)h2 | ((unsigned)h3 << 16));
    reinterpret_cast<uint2*>(lo)[i] =
        make_uint2((unsigned)g0 | ((unsigned)g1 << 16), (unsigned)g2 | ((unsigned)g3 << 16));
}

// W1 (192x256) -> w1; Wmu|Wlv (each 192x192) -> wml concatenated (384x192).
__global__ __launch_bounds__(256) void split_w_kernel(const float* __restrict__ W1,
                                                      const float* __restrict__ Wmu,
                                                      const float* __restrict__ Wlv,
                                                      unsigned short* __restrict__ w1h,
                                                      unsigned short* __restrict__ w1l,
                                                      unsigned short* __restrict__ wmlh,
                                                      unsigned short* __restrict__ wmll) {
    int i = blockIdx.x * 256 + threadIdx.x;      // quad index
    const float* src; unsigned short* dh; unsigned short* dl; int qi;
    if (i < 12288)      { src = W1;  dh = w1h;          dl = w1l;          qi = i; }
    else if (i < 21504) { src = Wmu; dh = wmlh;         dl = wmll;         qi = i - 12288; }
    else if (i < 30720) { src = Wlv; dh = wmlh + 36864; dl = wmll + 36864; qi = i - 21504; }
    else return;
    float4 v = reinterpret_cast<const float4*>(src)[qi];
    unsigned short h0 = f2bf(v.x), h1 = f2bf(v.y), h2 = f2bf(v.z), h3 = f2bf(v.w);
    unsigned short g0 = f2bf(v.x - bf2f(h0)), g1 = f2bf(v.y - bf2f(h1));
    unsigned short g2 = f2bf(v.z - bf2f(h2)), g3 = f2bf(v.w - bf2f(h3));
    reinterpret_cast<uint2*>(dh)[qi] =
        make_uint2((unsigned)h0 | ((unsigned)h1 << 16), (unsigned)h2 | ((unsigned)h3 << 16));
    reinterpret_cast<uint2*>(dl)[qi] =
        make_uint2((unsigned)g0 | ((unsigned)g1 << 16), (unsigned)g2 | ((unsigned)g3 << 16));
}

// ---------------------------------------------------------------------------
// Split-bf16 MFMA GEMM on pre-split inputs: C = A * B^T, fp16 out.
// BM=128, BN=64, BK=32; 256 threads = 4 waves (2x2), wave tile 64x32.
// K-loop staging is pure uint4 loads -> ds_write_b128 (no conversions).
// ---------------------------------------------------------------------------
#define LSTR 40
__device__ __forceinline__ void gemm_core(const unsigned short* __restrict__ Ahg,
                                          const unsigned short* __restrict__ Alg,
                                          const unsigned short* __restrict__ Bhg,
                                          const unsigned short* __restrict__ Blg,
                                          __half* __restrict__ C,
                                          int M, int CS, int K) {
    __shared__ unsigned short Ah[128 * LSTR], Al[128 * LSTR];
    __shared__ unsigned short Bh[64 * LSTR],  Bl[64 * LSTR];

    const int tid  = threadIdx.x;
    const int lane = tid & 63;
    const int wid  = tid >> 6;
    const int wm   = wid & 1;
    const int wn   = wid >> 1;
    const int quad = lane >> 4;
    const int l15  = lane & 15;
    const int m0   = blockIdx.x * 128;
    const int n0   = blockIdx.y * 64;

    const int srow = tid >> 2;       // 0..63
    const int scol = (tid & 3) * 8;  // ushort offset: 0,8,16,24

    f32x4 acc[4][2];
#pragma unroll
    for (int i = 0; i < 4; i++)
#pragma unroll
        for (int j = 0; j < 2; j++) acc[i][j] = (f32x4)(0.f);

    for (int k0 = 0; k0 < K; k0 += 32) {
        // ---- A tile 128x32: 2 passes of 64 rows, 16B per thread per array ----
#pragma unroll
        for (int p = 0; p < 2; p++) {
            int r = srow + p * 64;
            int gm = m0 + r;
            uint4 vh = make_uint4(0, 0, 0, 0), vl = make_uint4(0, 0, 0, 0);
            if (gm < M) {
                size_t gofs = (size_t)gm * K + k0 + scol;
                vh = *reinterpret_cast<const uint4*>(&Ahg[gofs]);
                vl = *reinterpret_cast<const uint4*>(&Alg[gofs]);
            }
            int lofs = r * LSTR + scol;
            *reinterpret_cast<uint4*>(&Ah[lofs]) = vh;
            *reinterpret_cast<uint4*>(&Al[lofs]) = vl;
        }
        // ---- B tile 64x32: 1 pass ----
        {
            size_t gofs = (size_t)(n0 + srow) * K + k0 + scol;
            uint4 vh = *reinterpret_cast<const uint4*>(&Bhg[gofs]);
            uint4 vl = *reinterpret_cast<const uint4*>(&Blg[gofs]);
            int lofs = srow * LSTR + scol;
            *reinterpret_cast<uint4*>(&Bh[lofs]) = vh;
            *reinterpret_cast<uint4*>(&Bl[lofs]) = vl;
        }
        __syncthreads();

        short8 afh[4], afl[4], bfh[2], bfl[2];
#pragma unroll
        for (int tm = 0; tm < 4; tm++) {
            int off = (wm * 64 + tm * 16 + l15) * LSTR + quad * 8;
            afh[tm] = *reinterpret_cast<const short8*>(&Ah[off]);
            afl[tm] = *reinterpret_cast<const short8*>(&Al[off]);
        }
#pragma unroll
        for (int tn = 0; tn < 2; tn++) {
            int off = (wn * 32 + tn * 16 + l15) * LSTR + quad * 8;
            bfh[tn] = *reinterpret_cast<const short8*>(&Bh[off]);
            bfl[tn] = *reinterpret_cast<const short8*>(&Bl[off]);
        }
#pragma unroll
        for (int tm = 0; tm < 4; tm++)
#pragma unroll
            for (int tn = 0; tn < 2; tn++) {
                acc[tm][tn] = __builtin_amdgcn_mfma_f32_16x16x32_bf16(afh[tm], bfh[tn], acc[tm][tn], 0, 0, 0);
                acc[tm][tn] = __builtin_amdgcn_mfma_f32_16x16x32_bf16(afh[tm], bfl[tn], acc[tm][tn], 0, 0, 0);
                acc[tm][tn] = __builtin_amdgcn_mfma_f32_16x16x32_bf16(afl[tm], bfh[tn], acc[tm][tn], 0, 0, 0);
            }
        __syncthreads();
    }

#pragma unroll
    for (int tm = 0; tm < 4; tm++) {
        int rbase = m0 + wm * 64 + tm * 16 + quad * 4;
#pragma unroll
        for (int r = 0; r < 4; r++) {
            int row = rbase + r;
            if (row < M) {
#pragma unroll
                for (int tn = 0; tn < 2; tn++) {
                    int col = n0 + wn * 32 + tn * 16 + l15;
                    C[(size_t)row * CS + col] = __float2half(acc[tm][tn][r]);
                }
            }
        }
    }
}

__global__ __launch_bounds__(256) void sgemm1(const unsigned short* __restrict__ Ah,
                                              const unsigned short* __restrict__ Al,
                                              const unsigned short* __restrict__ Bh,
                                              const unsigned short* __restrict__ Bl,
                                              __half* __restrict__ C) {
    gemm_core(Ah, Al, Bh, Bl, C, NN, HC, FIN);
}

__global__ __launch_bounds__(256) void sgemm23(const unsigned short* __restrict__ Ah,
                                               const unsigned short* __restrict__ Al,
                                               const unsigned short* __restrict__ Bh,
                                               const unsigned short* __restrict__ Bl,
                                               __half* __restrict__ C) {
    gemm_core(Ah, Al, Bh, Bl, C, NN, MLW, HC);
}

// ---------------------------------------------------------------------------
// Attention logits, layer 1 (h stride HC)
// ---------------------------------------------------------------------------
__global__ __launch_bounds__(256) void al_h_kernel(const __half* __restrict__ h,
                                                   const float* __restrict__ a_src,
                                                   const float* __restrict__ a_dst,
                                                   float* __restrict__ al_src,
                                                   float* __restrict__ al_dst) {
    int wid = (blockIdx.x * 256 + threadIdx.x) >> 6;
    int lane = threadIdx.x & 63;
    if (wid >= NN * NHEAD) return;
    int n = wid / 3;
    int head = wid - n * 3;
    float v = __half2float(h[(size_t)n * HC + head * CDIM + lane]);
    float ps = v * a_src[head * CDIM + lane];
    float pd = v * a_dst[head * CDIM + lane];
#pragma unroll
    for (int off = 32; off; off >>= 1) {
        ps += __shfl_xor(ps, off);
        pd += __shfl_xor(pd, off);
    }
    if (lane == 0) { al_src[wid] = ps; al_dst[wid] = pd; }
}

// Fused mu+lv logits from hml (stride MLW): 4 outputs in one pass.
__global__ __launch_bounds__(256) void al_ml_kernel(const __half* __restrict__ hml,
                                                    const float* __restrict__ amus,
                                                    const float* __restrict__ amud,
                                                    const float* __restrict__ alvs,
                                                    const float* __restrict__ alvd,
                                                    float* __restrict__ alms,
                                                    float* __restrict__ almd,
                                                    float* __restrict__ alls,
                                                    float* __restrict__ alld) {
    int wid = (blockIdx.x * 256 + threadIdx.x) >> 6;
    int lane = threadIdx.x & 63;
    if (wid >= NN * NHEAD) return;
    int n = wid / 3;
    int head = wid - n * 3;
    int c = head * CDIM + lane;
    float vm = __half2float(hml[(size_t)n * MLW + c]);
    float vl = __half2float(hml[(size_t)n * MLW + 192 + c]);
    float ms = vm * amus[c], md = vm * amud[c];
    float ls = vl * alvs[c], ld = vl * alvd[c];
#pragma unroll
    for (int off = 32; off; off >>= 1) {
        ms += __shfl_xor(ms, off);
        md += __shfl_xor(md, off);
        ls += __shfl_xor(ls, off);
        ld += __shfl_xor(ld, off);
    }
    if (lane == 0) { alms[wid] = ms; almd[wid] = md; alls[wid] = ls; alld[wid] = ld; }
}

// ---------------------------------------------------------------------------
// Per-wave softmax weights into LDS; returns softmax denominator.
// ---------------------------------------------------------------------------
__device__ __forceinline__ float edge_weights(const int* slds3, float* wrow,
                                              const float* __restrict__ al_s,
                                              float ad, int head, int deg, int lane) {
    float m = -1e30f;
    for (int j = lane; j < deg; j += 64) {
        float a = al_s[slds3[j] + head] + ad;
        a = a > 0.f ? a : 0.2f * a;
        wrow[j] = a;
        m = fmaxf(m, a);
    }
#pragma unroll
    for (int off = 32; off; off >>= 1) m = fmaxf(m, __shfl_xor(m, off));
    float ssum = 0.f;
    for (int j = lane; j < deg; j += 64) {
        float w = __expf(wrow[j] - m);
        wrow[j] = w;
        ssum += w;
    }
#pragma unroll
    for (int off = 32; off; off >>= 1) ssum += __shfl_xor(ssum, off);
    return ssum;
}

__device__ __forceinline__ float4 fma4h(float w, uint2 u, float4 acc) {
    __half2 p0 = *reinterpret_cast<__half2*>(&u.x);
    __half2 p1 = *reinterpret_cast<__half2*>(&u.y);
    float2 f0 = __half22float2(p0);
    float2 f1 = __half22float2(p1);
    acc.x = fmaf(w, f0.x, acc.x); acc.y = fmaf(w, f0.y, acc.y);
    acc.z = fmaf(w, f1.x, acc.z); acc.w = fmaf(w, f1.y, acc.w);
    return acc;
}

// ---------------------------------------------------------------------------
// Layer-1 aggregation (concat + bias + relu). 3 waves/node, fp16 h.
// Epilogue writes hrelu as pre-split bf16 hi/lo (feeds sgemm23 directly).
// ---------------------------------------------------------------------------
__global__ __launch_bounds__(192) void agg_cat_kernel(const int* __restrict__ row_ptr,
                                                      const int* __restrict__ csr_src,
                                                      const __half* __restrict__ h,
                                                      const float* __restrict__ al_src,
                                                      const float* __restrict__ al_dst,
                                                      const float* __restrict__ bias,
                                                      unsigned short* __restrict__ out_hi,
                                                      unsigned short* __restrict__ out_lo) {
    __shared__ int slds3[MAXDEG];
    __shared__ int sldsHC[MAXDEG];
    __shared__ float wlds[3][MAXDEG];
    int n = blockIdx.x;
    int head = threadIdx.x >> 6;
    int lane = threadIdx.x & 63;
    int start = row_ptr[n];
    int deg = row_ptr[n + 1] - start;
    float ad = al_dst[n * 3 + head];

    if (deg <= MAXDEG) {
        if (threadIdx.x < deg) {
            int s = csr_src[start + threadIdx.x];
            slds3[threadIdx.x] = s * 3;
            sldsHC[threadIdx.x] = s * HC;
        }
        __syncthreads();
        float ssum = edge_weights(slds3, wlds[head], al_src, ad, head, deg, lane);
        const int sub = lane >> 4, l16 = lane & 15;
        const int hoff = head * CDIM + l16 * 4;
        const float* wrow = wlds[head];
        float4 acc = make_float4(0.f, 0.f, 0.f, 0.f);
        int j = 0;
        for (; j + 16 <= deg; j += 16) {
            int s0 = sldsHC[j + sub],      s1 = sldsHC[j + 4 + sub];
            int s2 = sldsHC[j + 8 + sub],  s3 = sldsHC[j + 12 + sub];
            float w0 = wrow[j + sub],      w1 = wrow[j + 4 + sub];
            float w2 = wrow[j + 8 + sub],  w3 = wrow[j + 12 + sub];
            uint2 u0 = *reinterpret_cast<const uint2*>(&h[s0 + hoff]);
            uint2 u1 = *reinterpret_cast<const uint2*>(&h[s1 + hoff]);
            uint2 u2 = *reinterpret_cast<const uint2*>(&h[s2 + hoff]);
            uint2 u3 = *reinterpret_cast<const uint2*>(&h[s3 + hoff]);
            acc = fma4h(w0, u0, acc); acc = fma4h(w1, u1, acc);
            acc = fma4h(w2, u2, acc); acc = fma4h(w3, u3, acc);
        }
        for (; j + 4 <= deg; j += 4) {
            int s = sldsHC[j + sub];
            float w = wrow[j + sub];
            uint2 u = *reinterpret_cast<const uint2*>(&h[s + hoff]);
            acc = fma4h(w, u, acc);
        }
        if (sub < deg - j) {
            int s = sldsHC[j + sub];
            float w = wrow[j + sub];
            uint2 u = *reinterpret_cast<const uint2*>(&h[s + hoff]);
            acc = fma4h(w, u, acc);
        }
#pragma unroll
        for (int off = 16; off <= 32; off <<= 1) {
            acc.x += __shfl_xor(acc.x, off);
            acc.y += __shfl_xor(acc.y, off);
            acc.z += __shfl_xor(acc.z, off);
            acc.w += __shfl_xor(acc.w, off);
        }
        if (lane < 16) {
            float inv = 1.f / (ssum + 1e-16f);
            const float4 b4 = *reinterpret_cast<const float4*>(&bias[head * CDIM + l16 * 4]);
            float4 o;
            o.x = fmaxf(fmaf(acc.x, inv, b4.x), 0.f);
            o.y = fmaxf(fmaf(acc.y, inv, b4.y), 0.f);
            o.z = fmaxf(fmaf(acc.z, inv, b4.z), 0.f);
            o.w = fmaxf(fmaf(acc.w, inv, b4.w), 0.f);
            unsigned short h0 = f2bf(o.x), h1 = f2bf(o.y), h2 = f2bf(o.z), h3 = f2bf(o.w);
            unsigned short g0 = f2bf(o.x - bf2f(h0)), g1 = f2bf(o.y - bf2f(h1));
            unsigned short g2 = f2bf(o.z - bf2f(h2)), g3 = f2bf(o.w - bf2f(h3));
            size_t oofs = (size_t)n * HC + head * CDIM + l16 * 4;
            *reinterpret_cast<uint2*>(&out_hi[oofs]) =
                make_uint2((unsigned)h0 | ((unsigned)h1 << 16), (unsigned)h2 | ((unsigned)h3 << 16));
            *reinterpret_cast<uint2*>(&out_lo[oofs]) =
                make_uint2((unsigned)g0 | ((unsigned)g1 << 16), (unsigned)g2 | ((unsigned)g3 << 16));
        }
    } else {  // streaming fallback (not hit for this graph; correctness-safe)
        float m = -1e30f;
        for (int j = start + lane; j < start + deg; j += 64) {
            float a = al_src[csr_src[j] * 3 + head] + ad;
            a = a > 0.f ? a : 0.2f * a;
            m = fmaxf(m, a);
        }
#pragma unroll
        for (int off = 32; off; off >>= 1) m = fmaxf(m, __shfl_xor(m, off));
        float acc = 0.f, ssum = 0.f;
        for (int j = start; j < start + deg; ++j) {
            int s = csr_src[j];
            float a = al_src[s * 3 + head] + ad;
            a = a > 0.f ? a : 0.2f * a;
            float w = __expf(a - m);
            ssum += w;
            acc = fmaf(w, __half2float(h[(size_t)s * HC + head * CDIM + lane]), acc);
        }
        float o = acc / (ssum + 1e-16f) + bias[head * CDIM + lane];
        o = fmaxf(o, 0.f);
        unsigned short hh = f2bf(o);
        size_t oofs = (size_t)n * HC + head * CDIM + lane;
        out_hi[oofs] = hh;
        out_lo[oofs] = f2bf(o - bf2f(hh));
    }
}

// ---------------------------------------------------------------------------
// mu/lv aggregation fused over interleaved hml[n][384]: 3 waves/node, each
// wave = one head, both mu & lv; 16 edges/iter -> 8 loads in flight.
// ---------------------------------------------------------------------------
__global__ __launch_bounds__(192) void agg_mean2_kernel(const int* __restrict__ row_ptr,
                                                        const int* __restrict__ csr_src,
                                                        const __half* __restrict__ hml,
                                                        const float* __restrict__ alms,
                                                        const float* __restrict__ almd,
                                                        const float* __restrict__ alls,
                                                        const float* __restrict__ alld,
                                                        const float* __restrict__ b_mu,
                                                        const float* __restrict__ b_lv,
                                                        float* __restrict__ out) {
    __shared__ int slds3[MAXDEG];
    __shared__ int sldsML[MAXDEG];
    __shared__ float wm_[3][MAXDEG], wl_[3][MAXDEG];
    __shared__ __align__(16) float red[6][64];
    int n = blockIdx.x;
    int head = threadIdx.x >> 6;   // 0..2
    int lane = threadIdx.x & 63;
    int start = row_ptr[n];
    int deg = row_ptr[n + 1] - start;
    float adm = almd[n * 3 + head];
    float adl = alld[n * 3 + head];

    if (deg <= MAXDEG) {
        if (threadIdx.x < deg) {
            int s = csr_src[start + threadIdx.x];
            slds3[threadIdx.x] = s * 3;
            sldsML[threadIdx.x] = s * MLW;
        }
        __syncthreads();
        // softmax weights for mu and lv, interleaved
        float mm = -1e30f, ml = -1e30f;
        for (int j = lane; j < deg; j += 64) {
            int idx = slds3[j] + head;
            float am = alms[idx] + adm;
            float av = alls[idx] + adl;
            am = am > 0.f ? am : 0.2f * am;
            av = av > 0.f ? av : 0.2f * av;
            wm_[head][j] = am; wl_[head][j] = av;
            mm = fmaxf(mm, am); ml = fmaxf(ml, av);
        }
#pragma unroll
        for (int off = 32; off; off >>= 1) {
            mm = fmaxf(mm, __shfl_xor(mm, off));
            ml = fmaxf(ml, __shfl_xor(ml, off));
        }
        float sm = 0.f, sl = 0.f;
        for (int j = lane; j < deg; j += 64) {
            float em = __expf(wm_[head][j] - mm); wm_[head][j] = em; sm += em;
            float el = __expf(wl_[head][j] - ml); wl_[head][j] = el; sl += el;
        }
#pragma unroll
        for (int off = 32; off; off >>= 1) {
            sm += __shfl_xor(sm, off);
            sl += __shfl_xor(sl, off);
        }
        // joint gather: 8 loads in flight per iteration
        const int sub = lane >> 4, l16 = lane & 15;
        const int hoffm = head * CDIM + l16 * 4;
        const int hoffl = hoffm + 192;
        float4 am4 = make_float4(0.f, 0.f, 0.f, 0.f);
        float4 al4 = make_float4(0.f, 0.f, 0.f, 0.f);
        int j = 0;
        for (; j + 16 <= deg; j += 16) {
            int s0 = sldsML[j + sub],     s1 = sldsML[j + 4 + sub];
            int s2 = sldsML[j + 8 + sub], s3 = sldsML[j + 12 + sub];
            float wm0 = wm_[head][j + sub],      wm1 = wm_[head][j + 4 + sub];
            float wm2 = wm_[head][j + 8 + sub],  wm3 = wm_[head][j + 12 + sub];
            float wl0 = wl_[head][j + sub],      wl1 = wl_[head][j + 4 + sub];
            float wl2 = wl_[head][j + 8 + sub],  wl3 = wl_[head][j + 12 + sub];
            uint2 uM0 = *reinterpret_cast<const uint2*>(&hml[s0 + hoffm]);
            uint2 uL0 = *reinterpret_cast<const uint2*>(&hml[s0 + hoffl]);
            uint2 uM1 = *reinterpret_cast<const uint2*>(&hml[s1 + hoffm]);
            uint2 uL1 = *reinterpret_cast<const uint2*>(&hml[s1 + hoffl]);
            uint2 uM2 = *reinterpret_cast<const uint2*>(&hml[s2 + hoffm]);
            uint2 uL2 = *reinterpret_cast<const uint2*>(&hml[s2 + hoffl]);
            uint2 uM3 = *reinterpret_cast<const uint2*>(&hml[s3 + hoffm]);
            uint2 uL3 = *reinterpret_cast<const uint2*>(&hml[s3 + hoffl]);
            am4 = fma4h(wm0, uM0, am4); al4 = fma4h(wl0, uL0, al4);
            am4 = fma4h(wm1, uM1, am4); al4 = fma4h(wl1, uL1, al4);
            am4 = fma4h(wm2, uM2, am4); al4 = fma4h(wl2, uL2, al4);
            am4 = fma4h(wm3, uM3, am4); al4 = fma4h(wl3, uL3, al4);
        }
        for (; j + 4 <= deg; j += 4) {
            int s = sldsML[j + sub];
            float wmA = wm_[head][j + sub], wlA = wl_[head][j + sub];
            uint2 uM = *reinterpret_cast<const uint2*>(&hml[s + hoffm]);
            uint2 uL = *reinterpret_cast<const uint2*>(&hml[s + hoffl]);
            am4 = fma4h(wmA, uM, am4); al4 = fma4h(wlA, uL, al4);
        }
        if (sub < deg - j) {
            int s = sldsML[j + sub];
            float wmA = wm_[head][j + sub], wlA = wl_[head][j + sub];
            uint2 uM = *reinterpret_cast<const uint2*>(&hml[s + hoffm]);
            uint2 uL = *reinterpret_cast<const uint2*>(&hml[s + hoffl]);
            am4 = fma4h(wmA, uM, am4); al4 = fma4h(wlA, uL, al4);
        }
#pragma unroll
        for (int off = 16; off <= 32; off <<= 1) {
            am4.x += __shfl_xor(am4.x, off); am4.y += __shfl_xor(am4.y, off);
            am4.z += __shfl_xor(am4.z, off); am4.w += __shfl_xor(am4.w, off);
            al4.x += __shfl_xor(al4.x, off); al4.y += __shfl_xor(al4.y, off);
            al4.z += __shfl_xor(al4.z, off); al4.w += __shfl_xor(al4.w, off);
        }
        if (lane < 16) {
            float invm = 1.f / (sm + 1e-16f);
            float invl = 1.f / (sl + 1e-16f);
            float4 rm, rl;
            rm.x = am4.x * invm; rm.y = am4.y * invm; rm.z = am4.z * invm; rm.w = am4.w * invm;
            rl.x = al4.x * invl; rl.y = al4.y * invl; rl.z = al4.z * invl; rl.w = al4.w * invl;
            *reinterpret_cast<float4*>(&red[head][l16 * 4]) = rm;
            *reinterpret_cast<float4*>(&red[3 + head][l16 * 4]) = rl;
        }
    } else {  // streaming fallback (not hit; correctness-safe)
        for (int pass = 0; pass < 2; ++pass) {
            const float* as = pass ? alls : alms;
            float ad = pass ? adl : adm;
            int coff = pass ? 192 : 0;
            float m = -1e30f;
            for (int j = start + lane; j < start + deg; j += 64) {
                float a = as[csr_src[j] * 3 + head] + ad;
                a = a > 0.f ? a : 0.2f * a;
                m = fmaxf(m, a);
            }
#pragma unroll
            for (int off = 32; off; off >>= 1) m = fmaxf(m, __shfl_xor(m, off));
            float acc = 0.f, ssum = 0.f;
            for (int j = start; j < start + deg; ++j) {
                int s = csr_src[j];
                float a = as[s * 3 + head] + ad;
                a = a > 0.f ? a : 0.2f * a;
                float w = __expf(a - m);
                ssum += w;
                acc = fmaf(w, __half2float(hml[(size_t)s * MLW + coff + head * CDIM + lane]), acc);
            }
            red[pass * 3 + head][lane] = acc / (ssum + 1e-16f);
        }
    }
    __syncthreads();
    if (threadIdx.x < 64) {
        out[(size_t)n * CDIM + lane] =
            (red[0][lane] + red[1][lane] + red[2][lane]) * (1.f / 3.f) + b_mu[lane];
    } else if (threadIdx.x < 128) {
        out[(size_t)NN * CDIM + (size_t)n * CDIM + lane] =
            (red[3][lane] + red[4][lane] + red[5][lane]) * (1.f / 3.f) + b_lv[lane];
    }
}

// ---------------------------------------------------------------------------
extern "C" void kernel_launch(void* const* d_in, const int* in_sizes, int n_in,
                              void* d_out, int out_size, void* d_ws, size_t ws_size,
                              hipStream_t stream) {
    const float* x    = (const float*)d_in[0];
    const int*   ei   = (const int*)d_in[1];
    const float* W1   = (const float*)d_in[2];
    const float* a1s  = (const float*)d_in[3];
    const float* a1d  = (const float*)d_in[4];
    const float* b1   = (const float*)d_in[5];
    const float* Wmu  = (const float*)d_in[6];
    const float* amus = (const float*)d_in[7];
    const float* amud = (const float*)d_in[8];
    const float* bmu  = (const float*)d_in[9];
    const float* Wlv  = (const float*)d_in[10];
    const float* alvs = (const float*)d_in[11];
    const float* alvd = (const float*)d_in[12];
    const float* blv  = (const float*)d_in[13];
    float* out = (float*)d_out;

    // workspace carve (256B aligned)
    size_t off = 0;
    auto carve = [&](size_t bytes) {
        void* p = (char*)d_ws + off;
        off += (bytes + 255) & ~(size_t)255;
        return p;
    };
    int*    cnt      = (int*)carve((size_t)NN * 4);
    int*    row_ptr  = (int*)carve((size_t)(NN + 1) * 4);
    int*    partials = (int*)carve(64 * 4);
    int*    csr      = (int*)carve((size_t)ET * 4);
    __half* h1f16    = (__half*)carve((size_t)NN * HC * 2);
    __half* hml      = (__half*)carve((size_t)NN * MLW * 2);
    unsigned short* xh   = (unsigned short*)carve((size_t)NN * FIN * 2);
    unsigned short* xl   = (unsigned short*)carve((size_t)NN * FIN * 2);
    unsigned short* w1h  = (unsigned short*)carve((size_t)HC * FIN * 2);
    unsigned short* w1l  = (unsigned short*)carve((size_t)HC * FIN * 2);
    unsigned short* wmlh = (unsigned short*)carve((size_t)MLW * HC * 2);
    unsigned short* wmll = (unsigned short*)carve((size_t)MLW * HC * 2);
    unsigned short* hrh  = (unsigned short*)carve((size_t)NN * HC * 2);
    unsigned short* hrl  = (unsigned short*)carve((size_t)NN * HC * 2);
    float*  al1s     = (float*)carve((size_t)NN * 3 * 4);
    float*  al1d     = (float*)carve((size_t)NN * 3 * 4);
    float*  alms     = (float*)carve((size_t)NN * 3 * 4);
    float*  almd     = (float*)carve((size_t)NN * 3 * 4);
    float*  alls     = (float*)carve((size_t)NN * 3 * 4);
    float*  alld     = (float*)carve((size_t)NN * 3 * 4);

    const int scan_blocks = (NN + SCAN_BLK - 1) / SCAN_BLK;  // 49

    // ---- input splits (once per call) ----
    const int xquads = NN * FIN / 4;                          // 3.2M
    split_x_kernel<<<(xquads + 255) / 256, 256, 0, stream>>>(x, xh, xl, xquads);
    split_w_kernel<<<120, 256, 0, stream>>>(W1, Wmu, Wlv, w1h, w1l, wmlh, wmll);

    // ---- CSR build (shared by all 3 layers) ----
    hipMemsetAsync(cnt, 0, (size_t)NN * 4, stream);
    hist_kernel<<<(ET + 255) / 256, 256, 0, stream>>>(ei, cnt);
    scan1_kernel<<<scan_blocks, SCAN_BLK, 0, stream>>>(cnt, row_ptr, partials);
    scan2_kernel<<<1, 64, 0, stream>>>(partials, scan_blocks);
    scan3_kernel<<<scan_blocks, SCAN_BLK, 0, stream>>>(row_ptr, partials, cnt);
    scatter_kernel<<<(ET + 255) / 256, 256, 0, stream>>>(ei, cnt, row_ptr, csr);

    // ---- Layer 1 ----
    dim3 g1((NN + 127) / 128, HC / 64);
    sgemm1<<<g1, 256, 0, stream>>>(xh, xl, w1h, w1l, h1f16);
    al_h_kernel<<<(NN * 3 + 3) / 4, 256, 0, stream>>>(h1f16, a1s, a1d, al1s, al1d);
    agg_cat_kernel<<<NN, 192, 0, stream>>>(row_ptr, csr, h1f16, al1s, al1d, b1, hrh, hrl);

    // ---- Layers mu / lv fused: one GEMM (N=384), one al pass ----
    dim3 g2((NN + 127) / 128, MLW / 64);
    sgemm23<<<g2, 256, 0, stream>>>(hrh, hrl, wmlh, wmll, hml);
    al_ml_kernel<<<(NN * 3 + 3) / 4, 256, 0, stream>>>(hml, amus, amud, alvs, alvd,
                                                       alms, almd, alls, alld);
    agg_mean2_kernel<<<NN, 192, 0, stream>>>(row_ptr, csr, hml,
                                             alms, almd, alls, alld, bmu, blv, out);
}

// Round 9
// 551.833 us; speedup vs baseline: 1.0079x; 1.0079x over previous
//
#include <hip/hip_runtime.h>
#include <hip/hip_bf16.h>
#include <hip/hip_fp16.h>

// Problem constants (from reference)
#define NN 50000
#define NE 800000
#define ET (NE + NN)          // edges + self loops = 850000
#define FIN 256
#define HC 192                // H*C = 3*64
#define NHEAD 3
#define CDIM 64
#define MAXDEG 128            // fast-path cap; Poisson(17) max over 50K nodes ~45
#define MLW 384               // hml row width (mu 0..191 | lv 192..383)

typedef short short8 __attribute__((ext_vector_type(8)));
typedef float f32x4 __attribute__((ext_vector_type(4)));

// ---------------------------------------------------------------------------
// CSR build: histogram -> scan -> scatter (graph shared by all 3 GAT layers)
// ---------------------------------------------------------------------------
__global__ __launch_bounds__(256) void hist_kernel(const int* __restrict__ ei,
                                                   int* __restrict__ cnt) {
    int e = blockIdx.x * 256 + threadIdx.x;
    if (e >= ET) return;
    int dst = (e < NE) ? ei[NE + e] : (e - NE);
    atomicAdd(&cnt[dst], 1);
}

#define SCAN_BLK 1024
__global__ __launch_bounds__(SCAN_BLK) void scan1_kernel(const int* __restrict__ cnt,
                                                         int* __restrict__ row_ptr,
                                                         int* __restrict__ partials) {
    __shared__ int sm[SCAN_BLK];
    int t = threadIdx.x;
    int g = blockIdx.x * SCAN_BLK + t;
    int v = (g < NN) ? cnt[g] : 0;
    sm[t] = v;
    __syncthreads();
    for (int off = 1; off < SCAN_BLK; off <<= 1) {
        int u = (t >= off) ? sm[t - off] : 0;
        __syncthreads();
        sm[t] += u;
        __syncthreads();
    }
    if (g < NN) row_ptr[g + 1] = sm[t];
    if (t == SCAN_BLK - 1) partials[blockIdx.x] = sm[t];
}

__global__ __launch_bounds__(64) void scan2_kernel(int* __restrict__ partials, int nb) {
    int t = threadIdx.x;
    int v = (t < nb) ? partials[t] : 0;
    int x = v;
    for (int off = 1; off < 64; off <<= 1) {
        int y = __shfl_up(x, off);
        if (t >= off) x += y;
    }
    if (t < nb) partials[t] = x - v;
}

// also zeroes cnt so scatter can reuse it (saves a memset dispatch)
__global__ __launch_bounds__(SCAN_BLK) void scan3_kernel(int* __restrict__ row_ptr,
                                                         const int* __restrict__ partials,
                                                         int* __restrict__ cnt) {
    int g = blockIdx.x * SCAN_BLK + threadIdx.x;
    if (g < NN) {
        row_ptr[g + 1] += partials[blockIdx.x];
        cnt[g] = 0;
    }
    if (g == 0) row_ptr[0] = 0;
}

__global__ __launch_bounds__(256) void scatter_kernel(const int* __restrict__ ei,
                                                      int* __restrict__ cnt,
                                                      const int* __restrict__ row_ptr,
                                                      int* __restrict__ csr_src) {
    int e = blockIdx.x * 256 + threadIdx.x;
    if (e >= ET) return;
    int src, dst;
    if (e < NE) { src = ei[e]; dst = ei[NE + e]; }
    else        { src = e - NE; dst = e - NE; }
    int pos = atomicAdd(&cnt[dst], 1);
    csr_src[row_ptr[dst] + pos] = src;
}

// ---------------------------------------------------------------------------
// fp32 -> bf16 split helpers
// ---------------------------------------------------------------------------
__device__ __forceinline__ unsigned short f2bf(float f) {
    unsigned int u = __float_as_uint(f);
    unsigned int r = (u + 0x7FFFu + ((u >> 16) & 1u)) >> 16;   // RNE
    return (unsigned short)r;
}
__device__ __forceinline__ float bf2f(unsigned short h) {
    return __uint_as_float(((unsigned int)h) << 16);
}

// W1 (192x256) -> w1; Wmu|Wlv (each 192x192) -> wml concatenated (384x192).
__global__ __launch_bounds__(256) void split_w_kernel(const float* __restrict__ W1,
                                                      const float* __restrict__ Wmu,
                                                      const float* __restrict__ Wlv,
                                                      unsigned short* __restrict__ w1h,
                                                      unsigned short* __restrict__ w1l,
                                                      unsigned short* __restrict__ wmlh,
                                                      unsigned short* __restrict__ wmll) {
    int i = blockIdx.x * 256 + threadIdx.x;      // quad index
    const float* src; unsigned short* dh; unsigned short* dl; int qi;
    if (i < 12288)      { src = W1;  dh = w1h;          dl = w1l;          qi = i; }
    else if (i < 21504) { src = Wmu; dh = wmlh;         dl = wmll;         qi = i - 12288; }
    else if (i < 30720) { src = Wlv; dh = wmlh + 36864; dl = wmll + 36864; qi = i - 21504; }
    else return;
    float4 v = reinterpret_cast<const float4*>(src)[qi];
    unsigned short h0 = f2bf(v.x), h1 = f2bf(v.y), h2 = f2bf(v.z), h3 = f2bf(v.w);
    unsigned short g0 = f2bf(v.x - bf2f(h0)), g1 = f2bf(v.y - bf2f(h1));
    unsigned short g2 = f2bf(v.z - bf2f(h2)), g3 = f2bf(v.w - bf2f(h3));
    reinterpret_cast<uint2*>(dh)[qi] =
        make_uint2((unsigned)h0 | ((unsigned)h1 << 16), (unsigned)h2 | ((unsigned)h3 << 16));
    reinterpret_cast<uint2*>(dl)[qi] =
        make_uint2((unsigned)g0 | ((unsigned)g1 << 16), (unsigned)g2 | ((unsigned)g3 << 16));
}

// ---------------------------------------------------------------------------
// Split-bf16 MFMA GEMM: C = A * B^T, fp16 out.  BM=128, BN=192, BK=32.
// 256 threads = 4 waves (2x2), wave tile 64x96 (acc[4][6]).
// A: fp32 (converted on the fly) or pre-split hi/lo (template).
// B: always pre-split (weights or agg_cat epilogue output).
// ---------------------------------------------------------------------------
#define LSTR 40
template <bool PA>
__device__ __forceinline__ void gemm_core(const float* __restrict__ Af,
                                          const unsigned short* __restrict__ Ahg,
                                          const unsigned short* __restrict__ Alg,
                                          const unsigned short* __restrict__ Bhg,
                                          const unsigned short* __restrict__ Blg,
                                          __half* __restrict__ C,
                                          int M, int CS, int K) {
    __shared__ unsigned short Ah[128 * LSTR], Al[128 * LSTR];
    __shared__ unsigned short Bh[192 * LSTR], Bl[192 * LSTR];

    const int tid  = threadIdx.x;
    const int lane = tid & 63;
    const int wid  = tid >> 6;
    const int wm   = wid & 1;        // 0..1: m offset /64
    const int wn   = wid >> 1;       // 0..1: n offset /96
    const int quad = lane >> 4;
    const int l15  = lane & 15;
    const int m0   = blockIdx.x * 128;
    const int n0   = blockIdx.y * 192;

    f32x4 acc[4][6];
#pragma unroll
    for (int i = 0; i < 4; i++)
#pragma unroll
        for (int j = 0; j < 6; j++) acc[i][j] = (f32x4)(0.f);

    for (int k0 = 0; k0 < K; k0 += 32) {
        // ---- stage A 128x32 ----
        if (PA) {
            const int srow = tid >> 2, scol = (tid & 3) * 8;
#pragma unroll
            for (int p = 0; p < 2; p++) {
                int r = srow + p * 64;
                int gm = m0 + r;
                uint4 vh = make_uint4(0, 0, 0, 0), vl = make_uint4(0, 0, 0, 0);
                if (gm < M) {
                    size_t gofs = (size_t)gm * K + k0 + scol;
                    vh = *reinterpret_cast<const uint4*>(&Ahg[gofs]);
                    vl = *reinterpret_cast<const uint4*>(&Alg[gofs]);
                }
                int lofs = r * LSTR + scol;
                *reinterpret_cast<uint4*>(&Ah[lofs]) = vh;
                *reinterpret_cast<uint4*>(&Al[lofs]) = vl;
            }
        } else {
            const int srow = tid >> 3, scol = (tid & 7) * 4;
#pragma unroll
            for (int p = 0; p < 4; p++) {
                int r = srow + p * 32;
                int gm = m0 + r;
                float4 v = make_float4(0.f, 0.f, 0.f, 0.f);
                if (gm < M) v = *reinterpret_cast<const float4*>(&Af[(size_t)gm * K + k0 + scol]);
                unsigned short h0 = f2bf(v.x), h1 = f2bf(v.y), h2 = f2bf(v.z), h3 = f2bf(v.w);
                unsigned short g0 = f2bf(v.x - bf2f(h0)), g1 = f2bf(v.y - bf2f(h1));
                unsigned short g2 = f2bf(v.z - bf2f(h2)), g3 = f2bf(v.w - bf2f(h3));
                int lofs = r * LSTR + scol;
                *reinterpret_cast<uint2*>(&Ah[lofs]) =
                    make_uint2((unsigned)h0 | ((unsigned)h1 << 16), (unsigned)h2 | ((unsigned)h3 << 16));
                *reinterpret_cast<uint2*>(&Al[lofs]) =
                    make_uint2((unsigned)g0 | ((unsigned)g1 << 16), (unsigned)g2 | ((unsigned)g3 << 16));
            }
        }
        // ---- stage B 192x32 (pre-split) ----
        {
            const int srow = tid >> 2, scol = (tid & 3) * 8;
#pragma unroll
            for (int p = 0; p < 3; p++) {
                int r = srow + p * 64;
                size_t gofs = (size_t)(n0 + r) * K + k0 + scol;
                uint4 vh = *reinterpret_cast<const uint4*>(&Bhg[gofs]);
                uint4 vl = *reinterpret_cast<const uint4*>(&Blg[gofs]);
                int lofs = r * LSTR + scol;
                *reinterpret_cast<uint4*>(&Bh[lofs]) = vh;
                *reinterpret_cast<uint4*>(&Bl[lofs]) = vl;
            }
        }
        __syncthreads();

        short8 afh[4], afl[4], bfh[6], bfl[6];
#pragma unroll
        for (int tm = 0; tm < 4; tm++) {
            int off = (wm * 64 + tm * 16 + l15) * LSTR + quad * 8;
            afh[tm] = *reinterpret_cast<const short8*>(&Ah[off]);
            afl[tm] = *reinterpret_cast<const short8*>(&Al[off]);
        }
#pragma unroll
        for (int tn = 0; tn < 6; tn++) {
            int off = (wn * 96 + tn * 16 + l15) * LSTR + quad * 8;
            bfh[tn] = *reinterpret_cast<const short8*>(&Bh[off]);
            bfl[tn] = *reinterpret_cast<const short8*>(&Bl[off]);
        }
#pragma unroll
        for (int tm = 0; tm < 4; tm++)
#pragma unroll
            for (int tn = 0; tn < 6; tn++) {
                acc[tm][tn] = __builtin_amdgcn_mfma_f32_16x16x32_bf16(afh[tm], bfh[tn], acc[tm][tn], 0, 0, 0);
                acc[tm][tn] = __builtin_amdgcn_mfma_f32_16x16x32_bf16(afh[tm], bfl[tn], acc[tm][tn], 0, 0, 0);
                acc[tm][tn] = __builtin_amdgcn_mfma_f32_16x16x32_bf16(afl[tm], bfh[tn], acc[tm][tn], 0, 0, 0);
            }
        __syncthreads();
    }

#pragma unroll
    for (int tm = 0; tm < 4; tm++) {
        int rbase = m0 + wm * 64 + tm * 16 + quad * 4;
#pragma unroll
        for (int r = 0; r < 4; r++) {
            int row = rbase + r;
            if (row < M) {
#pragma unroll
                for (int tn = 0; tn < 6; tn++) {
                    int col = n0 + wn * 96 + tn * 16 + l15;
                    C[(size_t)row * CS + col] = __float2half(acc[tm][tn][r]);
                }
            }
        }
    }
}

__global__ __launch_bounds__(256) void sgemm1(const float* __restrict__ A,
                                              const unsigned short* __restrict__ Bh,
                                              const unsigned short* __restrict__ Bl,
                                              __half* __restrict__ C) {
    gemm_core<false>(A, nullptr, nullptr, Bh, Bl, C, NN, HC, FIN);
}

__global__ __launch_bounds__(256) void sgemm23(const unsigned short* __restrict__ Ah,
                                               const unsigned short* __restrict__ Al,
                                               const unsigned short* __restrict__ Bh,
                                               const unsigned short* __restrict__ Bl,
                                               __half* __restrict__ C) {
    gemm_core<true>(nullptr, Ah, Al, Bh, Bl, C, NN, MLW, HC);
}

// ---------------------------------------------------------------------------
// Attention logits, layer 1 (h stride HC)
// ---------------------------------------------------------------------------
__global__ __launch_bounds__(256) void al_h_kernel(const __half* __restrict__ h,
                                                   const float* __restrict__ a_src,
                                                   const float* __restrict__ a_dst,
                                                   float* __restrict__ al_src,
                                                   float* __restrict__ al_dst) {
    int wid = (blockIdx.x * 256 + threadIdx.x) >> 6;
    int lane = threadIdx.x & 63;
    if (wid >= NN * NHEAD) return;
    int n = wid / 3;
    int head = wid - n * 3;
    float v = __half2float(h[(size_t)n * HC + head * CDIM + lane]);
    float ps = v * a_src[head * CDIM + lane];
    float pd = v * a_dst[head * CDIM + lane];
#pragma unroll
    for (int off = 32; off; off >>= 1) {
        ps += __shfl_xor(ps, off);
        pd += __shfl_xor(pd, off);
    }
    if (lane == 0) { al_src[wid] = ps; al_dst[wid] = pd; }
}

// Fused mu+lv logits from hml (stride MLW): 4 outputs in one pass.
__global__ __launch_bounds__(256) void al_ml_kernel(const __half* __restrict__ hml,
                                                    const float* __restrict__ amus,
                                                    const float* __restrict__ amud,
                                                    const float* __restrict__ alvs,
                                                    const float* __restrict__ alvd,
                                                    float* __restrict__ alms,
                                                    float* __restrict__ almd,
                                                    float* __restrict__ alls,
                                                    float* __restrict__ alld) {
    int wid = (blockIdx.x * 256 + threadIdx.x) >> 6;
    int lane = threadIdx.x & 63;
    if (wid >= NN * NHEAD) return;
    int n = wid / 3;
    int head = wid - n * 3;
    int c = head * CDIM + lane;
    float vm = __half2float(hml[(size_t)n * MLW + c]);
    float vl = __half2float(hml[(size_t)n * MLW + 192 + c]);
    float ms = vm * amus[c], md = vm * amud[c];
    float ls = vl * alvs[c], ld = vl * alvd[c];
#pragma unroll
    for (int off = 32; off; off >>= 1) {
        ms += __shfl_xor(ms, off);
        md += __shfl_xor(md, off);
        ls += __shfl_xor(ls, off);
        ld += __shfl_xor(ld, off);
    }
    if (lane == 0) { alms[wid] = ms; almd[wid] = md; alls[wid] = ls; alld[wid] = ld; }
}

// ---------------------------------------------------------------------------
// Per-wave softmax weights into LDS; returns softmax denominator.
// ---------------------------------------------------------------------------
__device__ __forceinline__ float edge_weights(const int* slds3, float* wrow,
                                              const float* __restrict__ al_s,
                                              float ad, int head, int deg, int lane) {
    float m = -1e30f;
    for (int j = lane; j < deg; j += 64) {
        float a = al_s[slds3[j] + head] + ad;
        a = a > 0.f ? a : 0.2f * a;
        wrow[j] = a;
        m = fmaxf(m, a);
    }
#pragma unroll
    for (int off = 32; off; off >>= 1) m = fmaxf(m, __shfl_xor(m, off));
    float ssum = 0.f;
    for (int j = lane; j < deg; j += 64) {
        float w = __expf(wrow[j] - m);
        wrow[j] = w;
        ssum += w;
    }
#pragma unroll
    for (int off = 32; off; off >>= 1) ssum += __shfl_xor(ssum, off);
    return ssum;
}

__device__ __forceinline__ float4 fma4h(float w, uint2 u, float4 acc) {
    __half2 p0 = *reinterpret_cast<__half2*>(&u.x);
    __half2 p1 = *reinterpret_cast<__half2*>(&u.y);
    float2 f0 = __half22float2(p0);
    float2 f1 = __half22float2(p1);
    acc.x = fmaf(w, f0.x, acc.x); acc.y = fmaf(w, f0.y, acc.y);
    acc.z = fmaf(w, f1.x, acc.z); acc.w = fmaf(w, f1.y, acc.w);
    return acc;
}

// ---------------------------------------------------------------------------
// Layer-1 aggregation (concat + bias + relu). 3 waves/node, fp16 h.
// Epilogue writes hrelu as pre-split bf16 hi/lo (feeds sgemm23 directly).
// ---------------------------------------------------------------------------
__global__ __launch_bounds__(192) void agg_cat_kernel(const int* __restrict__ row_ptr,
                                                      const int* __restrict__ csr_src,
                                                      const __half* __restrict__ h,
                                                      const float* __restrict__ al_src,
                                                      const float* __restrict__ al_dst,
                                                      const float* __restrict__ bias,
                                                      unsigned short* __restrict__ out_hi,
                                                      unsigned short* __restrict__ out_lo) {
    __shared__ int slds3[MAXDEG];
    __shared__ int sldsHC[MAXDEG];
    __shared__ float wlds[3][MAXDEG];
    int n = blockIdx.x;
    int head = threadIdx.x >> 6;
    int lane = threadIdx.x & 63;
    int start = row_ptr[n];
    int deg = row_ptr[n + 1] - start;
    float ad = al_dst[n * 3 + head];

    if (deg <= MAXDEG) {
        if (threadIdx.x < deg) {
            int s = csr_src[start + threadIdx.x];
            slds3[threadIdx.x] = s * 3;
            sldsHC[threadIdx.x] = s * HC;
        }
        __syncthreads();
        float ssum = edge_weights(slds3, wlds[head], al_src, ad, head, deg, lane);
        const int sub = lane >> 4, l16 = lane & 15;
        const int hoff = head * CDIM + l16 * 4;
        const float* wrow = wlds[head];
        float4 acc = make_float4(0.f, 0.f, 0.f, 0.f);
        int j = 0;
        for (; j + 16 <= deg; j += 16) {
            int s0 = sldsHC[j + sub],      s1 = sldsHC[j + 4 + sub];
            int s2 = sldsHC[j + 8 + sub],  s3 = sldsHC[j + 12 + sub];
            float w0 = wrow[j + sub],      w1 = wrow[j + 4 + sub];
            float w2 = wrow[j + 8 + sub],  w3 = wrow[j + 12 + sub];
            uint2 u0 = *reinterpret_cast<const uint2*>(&h[s0 + hoff]);
            uint2 u1 = *reinterpret_cast<const uint2*>(&h[s1 + hoff]);
            uint2 u2 = *reinterpret_cast<const uint2*>(&h[s2 + hoff]);
            uint2 u3 = *reinterpret_cast<const uint2*>(&h[s3 + hoff]);
            acc = fma4h(w0, u0, acc); acc = fma4h(w1, u1, acc);
            acc = fma4h(w2, u2, acc); acc = fma4h(w3, u3, acc);
        }
        for (; j + 4 <= deg; j += 4) {
            int s = sldsHC[j + sub];
            float w = wrow[j + sub];
            uint2 u = *reinterpret_cast<const uint2*>(&h[s + hoff]);
            acc = fma4h(w, u, acc);
        }
        if (sub < deg - j) {
            int s = sldsHC[j + sub];
            float w = wrow[j + sub];
            uint2 u = *reinterpret_cast<const uint2*>(&h[s + hoff]);
            acc = fma4h(w, u, acc);
        }
#pragma unroll
        for (int off = 16; off <= 32; off <<= 1) {
            acc.x += __shfl_xor(acc.x, off);
            acc.y += __shfl_xor(acc.y, off);
            acc.z += __shfl_xor(acc.z, off);
            acc.w += __shfl_xor(acc.w, off);
        }
        if (lane < 16) {
            float inv = 1.f / (ssum + 1e-16f);
            const float4 b4 = *reinterpret_cast<const float4*>(&bias[head * CDIM + l16 * 4]);
            float4 o;
            o.x = fmaxf(fmaf(acc.x, inv, b4.x), 0.f);
            o.y = fmaxf(fmaf(acc.y, inv, b4.y), 0.f);
            o.z = fmaxf(fmaf(acc.z, inv, b4.z), 0.f);
            o.w = fmaxf(fmaf(acc.w, inv, b4.w), 0.f);
            unsigned short h0 = f2bf(o.x), h1 = f2bf(o.y), h2 = f2bf(o.z), h3 = f2bf(o.w);
            unsigned short g0 = f2bf(o.x - bf2f(h0)), g1 = f2bf(o.y - bf2f(h1));
            unsigned short g2 = f2bf(o.z - bf2f(h2)), g3 = f2bf(o.w - bf2f(h3));
            size_t oofs = (size_t)n * HC + head * CDIM + l16 * 4;
            *reinterpret_cast<uint2*>(&out_hi[oofs]) =
                make_uint2((unsigned)h0 | ((unsigned)h1 << 16), (unsigned)h2 | ((unsigned)h3 << 16));
            *reinterpret_cast<uint2*>(&out_lo[oofs]) =
                make_uint2((unsigned)g0 | ((unsigned)g1 << 16), (unsigned)g2 | ((unsigned)g3 << 16));
        }
    } else {  // streaming fallback (not hit for this graph; correctness-safe)
        float m = -1e30f;
        for (int j = start + lane; j < start + deg; j += 64) {
            float a = al_src[csr_src[j] * 3 + head] + ad;
            a = a > 0.f ? a : 0.2f * a;
            m = fmaxf(m, a);
        }
#pragma unroll
        for (int off = 32; off; off >>= 1) m = fmaxf(m, __shfl_xor(m, off));
        float acc = 0.f, ssum = 0.f;
        for (int j = start; j < start + deg; ++j) {
            int s = csr_src[j];
            float a = al_src[s * 3 + head] + ad;
            a = a > 0.f ? a : 0.2f * a;
            float w = __expf(a - m);
            ssum += w;
            acc = fmaf(w, __half2float(h[(size_t)s * HC + head * CDIM + lane]), acc);
        }
        float o = acc / (ssum + 1e-16f) + bias[head * CDIM + lane];
        o = fmaxf(o, 0.f);
        unsigned short hh = f2bf(o);
        size_t oofs = (size_t)n * HC + head * CDIM + lane;
        out_hi[oofs] = hh;
        out_lo[oofs] = f2bf(o - bf2f(hh));
    }
}

// ---------------------------------------------------------------------------
// mu/lv aggregation fused over interleaved hml[n][384]: 3 waves/node, each
// wave = one head, both mu & lv; 16 edges/iter -> 8 loads in flight.
// ---------------------------------------------------------------------------
__global__ __launch_bounds__(192) void agg_mean2_kernel(const int* __restrict__ row_ptr,
                                                        const int* __restrict__ csr_src,
                                                        const __half* __restrict__ hml,
                                                        const float* __restrict__ alms,
                                                        const float* __restrict__ almd,
                                                        const float* __restrict__ alls,
                                                        const float* __restrict__ alld,
                                                        const float* __restrict__ b_mu,
                                                        const float* __restrict__ b_lv,
                                                        float* __restrict__ out) {
    __shared__ int slds3[MAXDEG];
    __shared__ int sldsML[MAXDEG];
    __shared__ float wm_[3][MAXDEG], wl_[3][MAXDEG];
    __shared__ __align__(16) float red[6][64];
    int n = blockIdx.x;
    int head = threadIdx.x >> 6;   // 0..2
    int lane = threadIdx.x & 63;
    int start = row_ptr[n];
    int deg = row_ptr[n + 1] - start;
    float adm = almd[n * 3 + head];
    float adl = alld[n * 3 + head];

    if (deg <= MAXDEG) {
        if (threadIdx.x < deg) {
            int s = csr_src[start + threadIdx.x];
            slds3[threadIdx.x] = s * 3;
            sldsML[threadIdx.x] = s * MLW;
        }
        __syncthreads();
        // softmax weights for mu and lv, interleaved
        float mm = -1e30f, ml = -1e30f;
        for (int j = lane; j < deg; j += 64) {
            int idx = slds3[j] + head;
            float am = alms[idx] + adm;
            float av = alls[idx] + adl;
            am = am > 0.f ? am : 0.2f * am;
            av = av > 0.f ? av : 0.2f * av;
            wm_[head][j] = am; wl_[head][j] = av;
            mm = fmaxf(mm, am); ml = fmaxf(ml, av);
        }
#pragma unroll
        for (int off = 32; off; off >>= 1) {
            mm = fmaxf(mm, __shfl_xor(mm, off));
            ml = fmaxf(ml, __shfl_xor(ml, off));
        }
        float sm = 0.f, sl = 0.f;
        for (int j = lane; j < deg; j += 64) {
            float em = __expf(wm_[head][j] - mm); wm_[head][j] = em; sm += em;
            float el = __expf(wl_[head][j] - ml); wl_[head][j] = el; sl += el;
        }
#pragma unroll
        for (int off = 32; off; off >>= 1) {
            sm += __shfl_xor(sm, off);
            sl += __shfl_xor(sl, off);
        }
        // joint gather: 8 loads in flight per iteration
        const int sub = lane >> 4, l16 = lane & 15;
        const int hoffm = head * CDIM + l16 * 4;
        const int hoffl = hoffm + 192;
        float4 am4 = make_float4(0.f, 0.f, 0.f, 0.f);
        float4 al4 = make_float4(0.f, 0.f, 0.f, 0.f);
        int j = 0;
        for (; j + 16 <= deg; j += 16) {
            int s0 = sldsML[j + sub],     s1 = sldsML[j + 4 + sub];
            int s2 = sldsML[j + 8 + sub], s3 = sldsML[j + 12 + sub];
            float wm0 = wm_[head][j + sub],      wm1 = wm_[head][j + 4 + sub];
            float wm2 = wm_[head][j + 8 + sub],  wm3 = wm_[head][j + 12 + sub];
            float wl0 = wl_[head][j + sub],      wl1 = wl_[head][j + 4 + sub];
            float wl2 = wl_[head][j + 8 + sub],  wl3 = wl_[head][j + 12 + sub];
            uint2 uM0 = *reinterpret_cast<const uint2*>(&hml[s0 + hoffm]);
            uint2 uL0 = *reinterpret_cast<const uint2*>(&hml[s0 + hoffl]);
            uint2 uM1 = *reinterpret_cast<const uint2*>(&hml[s1 + hoffm]);
            uint2 uL1 = *reinterpret_cast<const uint2*>(&hml[s1 + hoffl]);
            uint2 uM2 = *reinterpret_cast<const uint2*>(&hml[s2 + hoffm]);
            uint2 uL2 = *reinterpret_cast<const uint2*>(&hml[s2 + hoffl]);
            uint2 uM3 = *reinterpret_cast<const uint2*>(&hml[s3 + hoffm]);
            uint2 uL3 = *reinterpret_cast<const uint2*>(&hml[s3 + hoffl]);
            am4 = fma4h(wm0, uM0, am4); al4 = fma4h(wl0, uL0, al4);
            am4 = fma4h(wm1, uM1, am4); al4 = fma4h(wl1, uL1, al4);
            am4 = fma4h(wm2, uM2, am4); al4 = fma4h(wl2, uL2, al4);
            am4 = fma4h(wm3, uM3, am4); al4 = fma4h(wl3, uL3, al4);
        }
        for (; j + 4 <= deg; j += 4) {
            int s = sldsML[j + sub];
            float wmA = wm_[head][j + sub], wlA = wl_[head][j + sub];
            uint2 uM = *reinterpret_cast<const uint2*>(&hml[s + hoffm]);
            uint2 uL = *reinterpret_cast<const uint2*>(&hml[s + hoffl]);
            am4 = fma4h(wmA, uM, am4); al4 = fma4h(wlA, uL, al4);
        }
        if (sub < deg - j) {
            int s = sldsML[j + sub];
            float wmA = wm_[head][j + sub], wlA = wl_[head][j + sub];
            uint2 uM = *reinterpret_cast<const uint2*>(&hml[s + hoffm]);
            uint2 uL = *reinterpret_cast<const uint2*>(&hml[s + hoffl]);
            am4 = fma4h(wmA, uM, am4); al4 = fma4h(wlA, uL, al4);
        }
#pragma unroll
        for (int off = 16; off <= 32; off <<= 1) {
            am4.x += __shfl_xor(am4.x, off); am4.y += __shfl_xor(am4.y, off);
            am4.z += __shfl_xor(am4.z, off); am4.w += __shfl_xor(am4.w, off);
            al4.x += __shfl_xor(al4.x, off); al4.y += __shfl_xor(al4.y, off);
            al4.z += __shfl_xor(al4.z, off); al4.w += __shfl_xor(al4.w, off);
        }
        if (lane < 16) {
            float invm = 1.f / (sm + 1e-16f);
            float invl = 1.f / (sl + 1e-16f);
            float4 rm, rl;
            rm.x = am4.x * invm; rm.y = am4.y * invm; rm.z = am4.z * invm; rm.w = am4.w * invm;
            rl.x = al4.x * invl; rl.y = al4.y * invl; rl.z = al4.z * invl; rl.w = al4.w * invl;
            *reinterpret_cast<float4*>(&red[head][l16 * 4]) = rm;
            *reinterpret_cast<float4*>(&red[3 + head][l16 * 4]) = rl;
        }
    } else {  // streaming fallback (not hit; correctness-safe)
        for (int pass = 0; pass < 2; ++pass) {
            const float* as = pass ? alls : alms;
            float ad = pass ? adl : adm;
            int coff = pass ? 192 : 0;
            float m = -1e30f;
            for (int j = start + lane; j < start + deg; j += 64) {
                float a = as[csr_src[j] * 3 + head] + ad;
                a = a > 0.f ? a : 0.2f * a;
                m = fmaxf(m, a);
            }
#pragma unroll
            for (int off = 32; off; off >>= 1) m = fmaxf(m, __shfl_xor(m, off));
            float acc = 0.f, ssum = 0.f;
            for (int j = start; j < start + deg; ++j) {
                int s = csr_src[j];
                float a = as[s * 3 + head] + ad;
                a = a > 0.f ? a : 0.2f * a;
                float w = __expf(a - m);
                ssum += w;
                acc = fmaf(w, __half2float(hml[(size_t)s * MLW + coff + head * CDIM + lane]), acc);
            }
            red[pass * 3 + head][lane] = acc / (ssum + 1e-16f);
        }
    }
    __syncthreads();
    if (threadIdx.x < 64) {
        out[(size_t)n * CDIM + lane] =
            (red[0][lane] + red[1][lane] + red[2][lane]) * (1.f / 3.f) + b_mu[lane];
    } else if (threadIdx.x < 128) {
        out[(size_t)NN * CDIM + (size_t)n * CDIM + lane] =
            (red[3][lane] + red[4][lane] + red[5][lane]) * (1.f / 3.f) + b_lv[lane];
    }
}

// ---------------------------------------------------------------------------
extern "C" void kernel_launch(void* const* d_in, const int* in_sizes, int n_in,
                              void* d_out, int out_size, void* d_ws, size_t ws_size,
                              hipStream_t stream) {
    const float* x    = (const float*)d_in[0];
    const int*   ei   = (const int*)d_in[1];
    const float* W1   = (const float*)d_in[2];
    const float* a1s  = (const float*)d_in[3];
    const float* a1d  = (const float*)d_in[4];
    const float* b1   = (const float*)d_in[5];
    const float* Wmu  = (const float*)d_in[6];
    const float* amus = (const float*)d_in[7];
    const float* amud = (const float*)d_in[8];
    const float* bmu  = (const float*)d_in[9];
    const float* Wlv  = (const float*)d_in[10];
    const float* alvs = (const float*)d_in[11];
    const float* alvd = (const float*)d_in[12];
    const float* blv  = (const float*)d_in[13];
    float* out = (float*)d_out;

    // workspace carve (256B aligned)
    size_t off = 0;
    auto carve = [&](size_t bytes) {
        void* p = (char*)d_ws + off;
        off += (bytes + 255) & ~(size_t)255;
        return p;
    };
    int*    cnt      = (int*)carve((size_t)NN * 4);
    int*    row_ptr  = (int*)carve((size_t)(NN + 1) * 4);
    int*    partials = (int*)carve(64 * 4);
    int*    csr      = (int*)carve((size_t)ET * 4);
    __half* h1f16    = (__half*)carve((size_t)NN * HC * 2);
    __half* hml      = (__half*)carve((size_t)NN * MLW * 2);
    unsigned short* w1h  = (unsigned short*)carve((size_t)HC * FIN * 2);
    unsigned short* w1l  = (unsigned short*)carve((size_t)HC * FIN * 2);
    unsigned short* wmlh = (unsigned short*)carve((size_t)MLW * HC * 2);
    unsigned short* wmll = (unsigned short*)carve((size_t)MLW * HC * 2);
    unsigned short* hrh  = (unsigned short*)carve((size_t)NN * HC * 2);
    unsigned short* hrl  = (unsigned short*)carve((size_t)NN * HC * 2);
    float*  al1s     = (float*)carve((size_t)NN * 3 * 4);
    float*  al1d     = (float*)carve((size_t)NN * 3 * 4);
    float*  alms     = (float*)carve((size_t)NN * 3 * 4);
    float*  almd     = (float*)carve((size_t)NN * 3 * 4);
    float*  alls     = (float*)carve((size_t)NN * 3 * 4);
    float*  alld     = (float*)carve((size_t)NN * 3 * 4);

    const int scan_blocks = (NN + SCAN_BLK - 1) / SCAN_BLK;  // 49

    // ---- weight splits (tiny, once per call) ----
    split_w_kernel<<<120, 256, 0, stream>>>(W1, Wmu, Wlv, w1h, w1l, wmlh, wmll);

    // ---- CSR build (shared by all 3 layers) ----
    hipMemsetAsync(cnt, 0, (size_t)NN * 4, stream);
    hist_kernel<<<(ET + 255) / 256, 256, 0, stream>>>(ei, cnt);
    scan1_kernel<<<scan_blocks, SCAN_BLK, 0, stream>>>(cnt, row_ptr, partials);
    scan2_kernel<<<1, 64, 0, stream>>>(partials, scan_blocks);
    scan3_kernel<<<scan_blocks, SCAN_BLK, 0, stream>>>(row_ptr, partials, cnt);
    scatter_kernel<<<(ET + 255) / 256, 256, 0, stream>>>(ei, cnt, row_ptr, csr);

    // ---- Layer 1: GEMM (single N-pass, BN=192) ----
    dim3 g1((NN + 127) / 128, 1);
    sgemm1<<<g1, 256, 0, stream>>>(x, w1h, w1l, h1f16);
    al_h_kernel<<<(NN * 3 + 3) / 4, 256, 0, stream>>>(h1f16, a1s, a1d, al1s, al1d);
    agg_cat_kernel<<<NN, 192, 0, stream>>>(row_ptr, csr, h1f16, al1s, al1d, b1, hrh, hrl);

    // ---- Layers mu / lv fused: one GEMM (N=384, 2 passes), one al pass ----
    dim3 g2((NN + 127) / 128, 2);
    sgemm23<<<g2, 256, 0, stream>>>(hrh, hrl, wmlh, wmll, hml);
    al_ml_kernel<<<(NN * 3 + 3) / 4, 256, 0, stream>>>(hml, amus, amud, alvs, alvd,
                                                       alms, almd, alls, alld);
    agg_mean2_kernel<<<NN, 192, 0, stream>>>(row_ptr, csr, hml,
                                             alms, almd, alls, alld, bmu, blv, out);
}

// Round 10
// 541.718 us; speedup vs baseline: 1.0267x; 1.0187x over previous
//
#include <hip/hip_runtime.h>
#include <hip/hip_bf16.h>
#include <hip/hip_fp16.h>

// Problem constants (from reference)
#define NN 50000
#define NE 800000
#define ET (NE + NN)          // edges + self loops = 850000
#define FIN 256
#define HC 192                // H*C = 3*64
#define NHEAD 3
#define CDIM 64
#define MAXDEG 128            // fast-path cap; Poisson(17) max over 50K nodes ~45
#define MLW 384               // hml row width (mu 0..191 | lv 192..383)

typedef short short8 __attribute__((ext_vector_type(8)));
typedef float f32x4 __attribute__((ext_vector_type(4)));

// ---------------------------------------------------------------------------
// fp32 -> bf16 split helpers
// ---------------------------------------------------------------------------
__device__ __forceinline__ unsigned short f2bf(float f) {
    unsigned int u = __float_as_uint(f);
    unsigned int r = (u + 0x7FFFu + ((u >> 16) & 1u)) >> 16;   // RNE
    return (unsigned short)r;
}
__device__ __forceinline__ float bf2f(unsigned short h) {
    return __uint_as_float(((unsigned int)h) << 16);
}

// ---------------------------------------------------------------------------
// split_w: weight hi/lo presplit + zero-init of cnt and scan aux (one dispatch)
// blocks 0..119: split W1 (12288 quads) / Wmu (9216) / Wlv (9216)
// blocks 120..: zero cnt[NN]; block 120 also zeroes scanaux[64]
// ---------------------------------------------------------------------------
__global__ __launch_bounds__(256) void split_w_kernel(const float* __restrict__ W1,
                                                      const float* __restrict__ Wmu,
                                                      const float* __restrict__ Wlv,
                                                      unsigned short* __restrict__ w1h,
                                                      unsigned short* __restrict__ w1l,
                                                      unsigned short* __restrict__ wmlh,
                                                      unsigned short* __restrict__ wmll,
                                                      int* __restrict__ cnt,
                                                      int* __restrict__ scanaux) {
    if (blockIdx.x >= 120) {
        int z = (blockIdx.x - 120) * 256 + threadIdx.x;
        if (z < NN) cnt[z] = 0;
        if (blockIdx.x == 120 && threadIdx.x < 64) scanaux[threadIdx.x] = 0;
        return;
    }
    int i = blockIdx.x * 256 + threadIdx.x;      // quad index < 30720
    const float* src; unsigned short* dh; unsigned short* dl; int qi;
    if (i < 12288)      { src = W1;  dh = w1h;          dl = w1l;          qi = i; }
    else if (i < 21504) { src = Wmu; dh = wmlh;         dl = wmll;         qi = i - 12288; }
    else                { src = Wlv; dh = wmlh + 36864; dl = wmll + 36864; qi = i - 21504; }
    float4 v = reinterpret_cast<const float4*>(src)[qi];
    unsigned short h0 = f2bf(v.x), h1 = f2bf(v.y), h2 = f2bf(v.z), h3 = f2bf(v.w);
    unsigned short g0 = f2bf(v.x - bf2f(h0)), g1 = f2bf(v.y - bf2f(h1));
    unsigned short g2 = f2bf(v.z - bf2f(h2)), g3 = f2bf(v.w - bf2f(h3));
    reinterpret_cast<uint2*>(dh)[qi] =
        make_uint2((unsigned)h0 | ((unsigned)h1 << 16), (unsigned)h2 | ((unsigned)h3 << 16));
    reinterpret_cast<uint2*>(dl)[qi] =
        make_uint2((unsigned)g0 | ((unsigned)g1 << 16), (unsigned)g2 | ((unsigned)g3 << 16));
}

// ---------------------------------------------------------------------------
// CSR build: histogram -> fused scan (decoupled lookback) -> scatter
// ---------------------------------------------------------------------------
__global__ __launch_bounds__(256) void hist_kernel(const int* __restrict__ ei,
                                                   int* __restrict__ cnt) {
    int e = blockIdx.x * 256 + threadIdx.x;
    if (e >= ET) return;
    int dst = (e < NE) ? ei[NE + e] : (e - NE);
    atomicAdd(&cnt[dst], 1);
}

#define SCAN_BLK 1024
// scanaux[0] = ticket; scanaux[1+b] = inclusive prefix of chunk b (0 = not ready;
// safe sentinel: every chunk total >= #nodes in chunk >= 1 due to self-loops).
// Also zeroes cnt for scatter reuse.
__global__ __launch_bounds__(SCAN_BLK) void scan_fused_kernel(int* __restrict__ cnt,
                                                              int* __restrict__ row_ptr,
                                                              int* __restrict__ scanaux) {
    __shared__ int sm[SCAN_BLK];
    __shared__ int bid_s, pre_s;
    int t = threadIdx.x;
    if (t == 0) bid_s = atomicAdd(&scanaux[0], 1);
    __syncthreads();
    int bid = bid_s;
    int g = bid * SCAN_BLK + t;
    int v = (g < NN) ? cnt[g] : 0;
    sm[t] = v;
    __syncthreads();
    for (int off = 1; off < SCAN_BLK; off <<= 1) {
        int u = (t >= off) ? sm[t - off] : 0;
        __syncthreads();
        sm[t] += u;
        __syncthreads();
    }
    if (t == 0) {
        int total = sm[SCAN_BLK - 1];
        int pre = 0;
        if (bid > 0) {
            while ((pre = __hip_atomic_load(&scanaux[bid], __ATOMIC_ACQUIRE,
                                            __HIP_MEMORY_SCOPE_AGENT)) == 0) {
                __builtin_amdgcn_s_sleep(8);
            }
        }
        __hip_atomic_store(&scanaux[bid + 1], pre + total, __ATOMIC_RELEASE,
                           __HIP_MEMORY_SCOPE_AGENT);
        pre_s = pre;
    }
    __syncthreads();
    int prefix = pre_s;
    if (g < NN) { row_ptr[g + 1] = sm[t] + prefix; cnt[g] = 0; }
    if (g == 0) row_ptr[0] = 0;
}

__global__ __launch_bounds__(256) void scatter_kernel(const int* __restrict__ ei,
                                                      int* __restrict__ cnt,
                                                      const int* __restrict__ row_ptr,
                                                      int* __restrict__ csr_src) {
    int e = blockIdx.x * 256 + threadIdx.x;
    if (e >= ET) return;
    int src, dst;
    if (e < NE) { src = ei[e]; dst = ei[NE + e]; }
    else        { src = e - NE; dst = e - NE; }
    int pos = atomicAdd(&cnt[dst], 1);
    csr_src[row_ptr[dst] + pos] = src;
}

// ---------------------------------------------------------------------------
// Split-bf16 MFMA GEMM: C = A * B^T, fp16 out. BM=128, BN=64, BK=32.
// 256 threads = 4 waves (2x2), wave tile 64x32 (acc[4][2]).
// BN=64 == one attention head -> fused al_src/al_dst epilogue (no extra pass).
// ---------------------------------------------------------------------------
#define LSTR 40
template <bool PA>
__device__ __forceinline__ void gemm_core(const float* __restrict__ Af,
                                          const unsigned short* __restrict__ Ahg,
                                          const unsigned short* __restrict__ Alg,
                                          const unsigned short* __restrict__ Bhg,
                                          const unsigned short* __restrict__ Blg,
                                          __half* __restrict__ C,
                                          int M, int CS, int K,
                                          const float* __restrict__ avs,
                                          const float* __restrict__ avd,
                                          float* __restrict__ als,
                                          float* __restrict__ ald,
                                          int head) {
    __shared__ unsigned short Ah[128 * LSTR], Al[128 * LSTR];
    __shared__ unsigned short Bh[64 * LSTR],  Bl[64 * LSTR];
    __shared__ __align__(16) float sal[128][4];   // {S_wn0, S_wn1, D_wn0, D_wn1}

    const int tid  = threadIdx.x;
    const int lane = tid & 63;
    const int wid  = tid >> 6;
    const int wm   = wid & 1;
    const int wn   = wid >> 1;
    const int quad = lane >> 4;
    const int l15  = lane & 15;
    const int m0   = blockIdx.x * 128;
    const int n0   = blockIdx.y * 64;

    f32x4 acc[4][2];
#pragma unroll
    for (int i = 0; i < 4; i++)
#pragma unroll
        for (int j = 0; j < 2; j++) acc[i][j] = (f32x4)(0.f);

    for (int k0 = 0; k0 < K; k0 += 32) {
        // ---- stage A 128x32 ----
        if (PA) {
            const int srow = tid >> 2, scol = (tid & 3) * 8;
#pragma unroll
            for (int p = 0; p < 2; p++) {
                int r = srow + p * 64;
                int gm = m0 + r;
                uint4 vh = make_uint4(0, 0, 0, 0), vl = make_uint4(0, 0, 0, 0);
                if (gm < M) {
                    size_t gofs = (size_t)gm * K + k0 + scol;
                    vh = *reinterpret_cast<const uint4*>(&Ahg[gofs]);
                    vl = *reinterpret_cast<const uint4*>(&Alg[gofs]);
                }
                int lofs = r * LSTR + scol;
                *reinterpret_cast<uint4*>(&Ah[lofs]) = vh;
                *reinterpret_cast<uint4*>(&Al[lofs]) = vl;
            }
        } else {
            const int srow = tid >> 3, scol = (tid & 7) * 4;
#pragma unroll
            for (int p = 0; p < 4; p++) {
                int r = srow + p * 32;
                int gm = m0 + r;
                float4 v = make_float4(0.f, 0.f, 0.f, 0.f);
                if (gm < M) v = *reinterpret_cast<const float4*>(&Af[(size_t)gm * K + k0 + scol]);
                unsigned short h0 = f2bf(v.x), h1 = f2bf(v.y), h2 = f2bf(v.z), h3 = f2bf(v.w);
                unsigned short g0 = f2bf(v.x - bf2f(h0)), g1 = f2bf(v.y - bf2f(h1));
                unsigned short g2 = f2bf(v.z - bf2f(h2)), g3 = f2bf(v.w - bf2f(h3));
                int lofs = r * LSTR + scol;
                *reinterpret_cast<uint2*>(&Ah[lofs]) =
                    make_uint2((unsigned)h0 | ((unsigned)h1 << 16), (unsigned)h2 | ((unsigned)h3 << 16));
                *reinterpret_cast<uint2*>(&Al[lofs]) =
                    make_uint2((unsigned)g0 | ((unsigned)g1 << 16), (unsigned)g2 | ((unsigned)g3 << 16));
            }
        }
        // ---- stage B 64x32 (pre-split) ----
        {
            const int srow = tid >> 2, scol = (tid & 3) * 8;
            size_t gofs = (size_t)(n0 + srow) * K + k0 + scol;
            uint4 vh = *reinterpret_cast<const uint4*>(&Bhg[gofs]);
            uint4 vl = *reinterpret_cast<const uint4*>(&Blg[gofs]);
            int lofs = srow * LSTR + scol;
            *reinterpret_cast<uint4*>(&Bh[lofs]) = vh;
            *reinterpret_cast<uint4*>(&Bl[lofs]) = vl;
        }
        __syncthreads();

        short8 afh[4], afl[4], bfh[2], bfl[2];
#pragma unroll
        for (int tm = 0; tm < 4; tm++) {
            int off = (wm * 64 + tm * 16 + l15) * LSTR + quad * 8;
            afh[tm] = *reinterpret_cast<const short8*>(&Ah[off]);
            afl[tm] = *reinterpret_cast<const short8*>(&Al[off]);
        }
#pragma unroll
        for (int tn = 0; tn < 2; tn++) {
            int off = (wn * 32 + tn * 16 + l15) * LSTR + quad * 8;
            bfh[tn] = *reinterpret_cast<const short8*>(&Bh[off]);
            bfl[tn] = *reinterpret_cast<const short8*>(&Bl[off]);
        }
#pragma unroll
        for (int tm = 0; tm < 4; tm++)
#pragma unroll
            for (int tn = 0; tn < 2; tn++) {
                acc[tm][tn] = __builtin_amdgcn_mfma_f32_16x16x32_bf16(afh[tm], bfh[tn], acc[tm][tn], 0, 0, 0);
                acc[tm][tn] = __builtin_amdgcn_mfma_f32_16x16x32_bf16(afh[tm], bfl[tn], acc[tm][tn], 0, 0, 0);
                acc[tm][tn] = __builtin_amdgcn_mfma_f32_16x16x32_bf16(afl[tm], bfh[tn], acc[tm][tn], 0, 0, 0);
            }
        __syncthreads();
    }

    // ---- C store ----
#pragma unroll
    for (int tm = 0; tm < 4; tm++) {
        int rbase = m0 + wm * 64 + tm * 16 + quad * 4;
#pragma unroll
        for (int r = 0; r < 4; r++) {
            int row = rbase + r;
            if (row < M) {
#pragma unroll
                for (int tn = 0; tn < 2; tn++) {
                    int col = n0 + wn * 32 + tn * 16 + l15;
                    C[(size_t)row * CS + col] = __float2half(acc[tm][tn][r]);
                }
            }
        }
    }

    // ---- fused al epilogue: this block's 64 cols == one head ----
    for (int i = tid; i < 128; i += 256) {
        sal[i][0] = 0.f; sal[i][1] = 0.f; sal[i][2] = 0.f; sal[i][3] = 0.f;
    }
    __syncthreads();
    float a_s[2], a_d[2];
#pragma unroll
    for (int tn = 0; tn < 2; tn++) {
        int cl = wn * 32 + tn * 16 + l15;
        a_s[tn] = avs[head * CDIM + cl];
        a_d[tn] = avd[head * CDIM + cl];
    }
#pragma unroll
    for (int tm = 0; tm < 4; tm++) {
#pragma unroll
        for (int r = 0; r < 4; r++) {
            float ps = acc[tm][0][r] * a_s[0] + acc[tm][1][r] * a_s[1];
            float pd = acc[tm][0][r] * a_d[0] + acc[tm][1][r] * a_d[1];
#pragma unroll
            for (int off = 1; off < 16; off <<= 1) {
                ps += __shfl_xor(ps, off);
                pd += __shfl_xor(pd, off);
            }
            if (l15 == 0) {
                int R = wm * 64 + tm * 16 + quad * 4 + r;
                sal[R][wn] = ps;
                sal[R][2 + wn] = pd;
            }
        }
    }
    __syncthreads();
    for (int i = tid; i < 128; i += 256) {
        int row = m0 + i;
        if (row < M) {
            als[row * 3 + head] = sal[i][0] + sal[i][1];
            ald[row * 3 + head] = sal[i][2] + sal[i][3];
        }
    }
}

__global__ __launch_bounds__(256) void sgemm1(const float* __restrict__ A,
                                              const unsigned short* __restrict__ Bh,
                                              const unsigned short* __restrict__ Bl,
                                              __half* __restrict__ C,
                                              const float* __restrict__ a1s,
                                              const float* __restrict__ a1d,
                                              float* __restrict__ al1s,
                                              float* __restrict__ al1d) {
    gemm_core<false>(A, nullptr, nullptr, Bh, Bl, C, NN, HC, FIN,
                     a1s, a1d, al1s, al1d, blockIdx.y);
}

__global__ __launch_bounds__(256) void sgemm23(const unsigned short* __restrict__ Ah,
                                               const unsigned short* __restrict__ Al,
                                               const unsigned short* __restrict__ Bh,
                                               const unsigned short* __restrict__ Bl,
                                               __half* __restrict__ C,
                                               const float* __restrict__ amus,
                                               const float* __restrict__ amud,
                                               const float* __restrict__ alvs,
                                               const float* __restrict__ alvd,
                                               float* __restrict__ alms,
                                               float* __restrict__ almd,
                                               float* __restrict__ alls,
                                               float* __restrict__ alld) {
    int y = blockIdx.y;
    const float* avs; const float* avd; float* als; float* ald; int head;
    if (y < 3) { avs = amus; avd = amud; als = alms; ald = almd; head = y; }
    else       { avs = alvs; avd = alvd; als = alls; ald = alld; head = y - 3; }
    gemm_core<true>(nullptr, Ah, Al, Bh, Bl, C, NN, MLW, HC,
                    avs, avd, als, ald, head);
}

// ---------------------------------------------------------------------------
// Per-wave softmax weights into LDS; returns softmax denominator.
// ---------------------------------------------------------------------------
__device__ __forceinline__ float edge_weights(const int* slds3, float* wrow,
                                              const float* __restrict__ al_s,
                                              float ad, int head, int deg, int lane) {
    float m = -1e30f;
    for (int j = lane; j < deg; j += 64) {
        float a = al_s[slds3[j] + head] + ad;
        a = a > 0.f ? a : 0.2f * a;
        wrow[j] = a;
        m = fmaxf(m, a);
    }
#pragma unroll
    for (int off = 32; off; off >>= 1) m = fmaxf(m, __shfl_xor(m, off));
    float ssum = 0.f;
    for (int j = lane; j < deg; j += 64) {
        float w = __expf(wrow[j] - m);
        wrow[j] = w;
        ssum += w;
    }
#pragma unroll
    for (int off = 32; off; off >>= 1) ssum += __shfl_xor(ssum, off);
    return ssum;
}

__device__ __forceinline__ float4 fma4h(float w, uint2 u, float4 acc) {
    __half2 p0 = *reinterpret_cast<__half2*>(&u.x);
    __half2 p1 = *reinterpret_cast<__half2*>(&u.y);
    float2 f0 = __half22float2(p0);
    float2 f1 = __half22float2(p1);
    acc.x = fmaf(w, f0.x, acc.x); acc.y = fmaf(w, f0.y, acc.y);
    acc.z = fmaf(w, f1.x, acc.z); acc.w = fmaf(w, f1.y, acc.w);
    return acc;
}

// ---------------------------------------------------------------------------
// Layer-1 aggregation (concat + bias + relu). 3 waves/node, fp16 h.
// Epilogue writes hrelu as pre-split bf16 hi/lo (feeds sgemm23 directly).
// ---------------------------------------------------------------------------
__global__ __launch_bounds__(192) void agg_cat_kernel(const int* __restrict__ row_ptr,
                                                      const int* __restrict__ csr_src,
                                                      const __half* __restrict__ h,
                                                      const float* __restrict__ al_src,
                                                      const float* __restrict__ al_dst,
                                                      const float* __restrict__ bias,
                                                      unsigned short* __restrict__ out_hi,
                                                      unsigned short* __restrict__ out_lo) {
    __shared__ int slds3[MAXDEG];
    __shared__ int sldsHC[MAXDEG];
    __shared__ float wlds[3][MAXDEG];
    int n = blockIdx.x;
    int head = threadIdx.x >> 6;
    int lane = threadIdx.x & 63;
    int start = row_ptr[n];
    int deg = row_ptr[n + 1] - start;
    float ad = al_dst[n * 3 + head];

    if (deg <= MAXDEG) {
        if (threadIdx.x < deg) {
            int s = csr_src[start + threadIdx.x];
            slds3[threadIdx.x] = s * 3;
            sldsHC[threadIdx.x] = s * HC;
        }
        __syncthreads();
        float ssum = edge_weights(slds3, wlds[head], al_src, ad, head, deg, lane);
        const int sub = lane >> 4, l16 = lane & 15;
        const int hoff = head * CDIM + l16 * 4;
        const float* wrow = wlds[head];
        float4 acc = make_float4(0.f, 0.f, 0.f, 0.f);
        int j = 0;
        for (; j + 16 <= deg; j += 16) {
            int s0 = sldsHC[j + sub],      s1 = sldsHC[j + 4 + sub];
            int s2 = sldsHC[j + 8 + sub],  s3 = sldsHC[j + 12 + sub];
            float w0 = wrow[j + sub],      w1 = wrow[j + 4 + sub];
            float w2 = wrow[j + 8 + sub],  w3 = wrow[j + 12 + sub];
            uint2 u0 = *reinterpret_cast<const uint2*>(&h[s0 + hoff]);
            uint2 u1 = *reinterpret_cast<const uint2*>(&h[s1 + hoff]);
            uint2 u2 = *reinterpret_cast<const uint2*>(&h[s2 + hoff]);
            uint2 u3 = *reinterpret_cast<const uint2*>(&h[s3 + hoff]);
            acc = fma4h(w0, u0, acc); acc = fma4h(w1, u1, acc);
            acc = fma4h(w2, u2, acc); acc = fma4h(w3, u3, acc);
        }
        for (; j + 4 <= deg; j += 4) {
            int s = sldsHC[j + sub];
            float w = wrow[j + sub];
            uint2 u = *reinterpret_cast<const uint2*>(&h[s + hoff]);
            acc = fma4h(w, u, acc);
        }
        if (sub < deg - j) {
            int s = sldsHC[j + sub];
            float w = wrow[j + sub];
            uint2 u = *reinterpret_cast<const uint2*>(&h[s + hoff]);
            acc = fma4h(w, u, acc);
        }
#pragma unroll
        for (int off = 16; off <= 32; off <<= 1) {
            acc.x += __shfl_xor(acc.x, off);
            acc.y += __shfl_xor(acc.y, off);
            acc.z += __shfl_xor(acc.z, off);
            acc.w += __shfl_xor(acc.w, off);
        }
        if (lane < 16) {
            float inv = 1.f / (ssum + 1e-16f);
            const float4 b4 = *reinterpret_cast<const float4*>(&bias[head * CDIM + l16 * 4]);
            float4 o;
            o.x = fmaxf(fmaf(acc.x, inv, b4.x), 0.f);
            o.y = fmaxf(fmaf(acc.y, inv, b4.y), 0.f);
            o.z = fmaxf(fmaf(acc.z, inv, b4.z), 0.f);
            o.w = fmaxf(fmaf(acc.w, inv, b4.w), 0.f);
            unsigned short h0 = f2bf(o.x), h1 = f2bf(o.y), h2 = f2bf(o.z), h3 = f2bf(o.w);
            unsigned short g0 = f2bf(o.x - bf2f(h0)), g1 = f2bf(o.y - bf2f(h1));
            unsigned short g2 = f2bf(o.z - bf2f(h2)), g3 = f2bf(o.w - bf2f(h3));
            size_t oofs = (size_t)n * HC + head * CDIM + l16 * 4;
            *reinterpret_cast<uint2*>(&out_hi[oofs]) =
                make_uint2((unsigned)h0 | ((unsigned)h1 << 16), (unsigned)h2 | ((unsigned)h3 << 16));
            *reinterpret_cast<uint2*>(&out_lo[oofs]) =
                make_uint2((unsigned)g0 | ((unsigned)g1 << 16), (unsigned)g2 | ((unsigned)g3 << 16));
        }
    } else {  // streaming fallback (not hit for this graph; correctness-safe)
        float m = -1e30f;
        for (int j = start + lane; j < start + deg; j += 64) {
            float a = al_src[csr_src[j] * 3 + head] + ad;
            a = a > 0.f ? a : 0.2f * a;
            m = fmaxf(m, a);
        }
#pragma unroll
        for (int off = 32; off; off >>= 1) m = fmaxf(m, __shfl_xor(m, off));
        float acc = 0.f, ssum = 0.f;
        for (int j = start; j < start + deg; ++j) {
            int s = csr_src[j];
            float a = al_src[s * 3 + head] + ad;
            a = a > 0.f ? a : 0.2f * a;
            float w = __expf(a - m);
            ssum += w;
            acc = fmaf(w, __half2float(h[(size_t)s * HC + head * CDIM + lane]), acc);
        }
        float o = acc / (ssum + 1e-16f) + bias[head * CDIM + lane];
        o = fmaxf(o, 0.f);
        unsigned short hh = f2bf(o);
        size_t oofs = (size_t)n * HC + head * CDIM + lane;
        out_hi[oofs] = hh;
        out_lo[oofs] = f2bf(o - bf2f(hh));
    }
}

// ---------------------------------------------------------------------------
// mu/lv aggregation fused over interleaved hml[n][384]: 3 waves/node, each
// wave = one head, both mu & lv; 16 edges/iter -> 8 loads in flight.
// ---------------------------------------------------------------------------
__global__ __launch_bounds__(192) void agg_mean2_kernel(const int* __restrict__ row_ptr,
                                                        const int* __restrict__ csr_src,
                                                        const __half* __restrict__ hml,
                                                        const float* __restrict__ alms,
                                                        const float* __restrict__ almd,
                                                        const float* __restrict__ alls,
                                                        const float* __restrict__ alld,
                                                        const float* __restrict__ b_mu,
                                                        const float* __restrict__ b_lv,
                                                        float* __restrict__ out) {
    __shared__ int slds3[MAXDEG];
    __shared__ int sldsML[MAXDEG];
    __shared__ float wm_[3][MAXDEG], wl_[3][MAXDEG];
    __shared__ __align__(16) float red[6][64];
    int n = blockIdx.x;
    int head = threadIdx.x >> 6;   // 0..2
    int lane = threadIdx.x & 63;
    int start = row_ptr[n];
    int deg = row_ptr[n + 1] - start;
    float adm = almd[n * 3 + head];
    float adl = alld[n * 3 + head];

    if (deg <= MAXDEG) {
        if (threadIdx.x < deg) {
            int s = csr_src[start + threadIdx.x];
            slds3[threadIdx.x] = s * 3;
            sldsML[threadIdx.x] = s * MLW;
        }
        __syncthreads();
        // softmax weights for mu and lv, interleaved
        float mm = -1e30f, ml = -1e30f;
        for (int j = lane; j < deg; j += 64) {
            int idx = slds3[j] + head;
            float am = alms[idx] + adm;
            float av = alls[idx] + adl;
            am = am > 0.f ? am : 0.2f * am;
            av = av > 0.f ? av : 0.2f * av;
            wm_[head][j] = am; wl_[head][j] = av;
            mm = fmaxf(mm, am); ml = fmaxf(ml, av);
        }
#pragma unroll
        for (int off = 32; off; off >>= 1) {
            mm = fmaxf(mm, __shfl_xor(mm, off));
            ml = fmaxf(ml, __shfl_xor(ml, off));
        }
        float sm = 0.f, sl = 0.f;
        for (int j = lane; j < deg; j += 64) {
            float em = __expf(wm_[head][j] - mm); wm_[head][j] = em; sm += em;
            float el = __expf(wl_[head][j] - ml); wl_[head][j] = el; sl += el;
        }
#pragma unroll
        for (int off = 32; off; off >>= 1) {
            sm += __shfl_xor(sm, off);
            sl += __shfl_xor(sl, off);
        }
        // joint gather: 8 loads in flight per iteration
        const int sub = lane >> 4, l16 = lane & 15;
        const int hoffm = head * CDIM + l16 * 4;
        const int hoffl = hoffm + 192;
        float4 am4 = make_float4(0.f, 0.f, 0.f, 0.f);
        float4 al4 = make_float4(0.f, 0.f, 0.f, 0.f);
        int j = 0;
        for (; j + 16 <= deg; j += 16) {
            int s0 = sldsML[j + sub],     s1 = sldsML[j + 4 + sub];
            int s2 = sldsML[j + 8 + sub], s3 = sldsML[j + 12 + sub];
            float wm0 = wm_[head][j + sub],      wm1 = wm_[head][j + 4 + sub];
            float wm2 = wm_[head][j + 8 + sub],  wm3 = wm_[head][j + 12 + sub];
            float wl0 = wl_[head][j + sub],      wl1 = wl_[head][j + 4 + sub];
            float wl2 = wl_[head][j + 8 + sub],  wl3 = wl_[head][j + 12 + sub];
            uint2 uM0 = *reinterpret_cast<const uint2*>(&hml[s0 + hoffm]);
            uint2 uL0 = *reinterpret_cast<const uint2*>(&hml[s0 + hoffl]);
            uint2 uM1 = *reinterpret_cast<const uint2*>(&hml[s1 + hoffm]);
            uint2 uL1 = *reinterpret_cast<const uint2*>(&hml[s1 + hoffl]);
            uint2 uM2 = *reinterpret_cast<const uint2*>(&hml[s2 + hoffm]);
            uint2 uL2 = *reinterpret_cast<const uint2*>(&hml[s2 + hoffl]);
            uint2 uM3 = *reinterpret_cast<const uint2*>(&hml[s3 + hoffm]);
            uint2 uL3 = *reinterpret_cast<const uint2*>(&hml[s3 + hoffl]);
            am4 = fma4h(wm0, uM0, am4); al4 = fma4h(wl0, uL0, al4);
            am4 = fma4h(wm1, uM1, am4); al4 = fma4h(wl1, uL1, al4);
            am4 = fma4h(wm2, uM2, am4); al4 = fma4h(wl2, uL2, al4);
            am4 = fma4h(wm3, uM3, am4); al4 = fma4h(wl3, uL3, al4);
        }
        for (; j + 4 <= deg; j += 4) {
            int s = sldsML[j + sub];
            float wmA = wm_[head][j + sub], wlA = wl_[head][j + sub];
            uint2 uM = *reinterpret_cast<const uint2*>(&hml[s + hoffm]);
            uint2 uL = *reinterpret_cast<const uint2*>(&hml[s + hoffl]);
            am4 = fma4h(wmA, uM, am4); al4 = fma4h(wlA, uL, al4);
        }
        if (sub < deg - j) {
            int s = sldsML[j + sub];
            float wmA = wm_[head][j + sub], wlA = wl_[head][j + sub];
            uint2 uM = *reinterpret_cast<const uint2*>(&hml[s + hoffm]);
            uint2 uL = *reinterpret_cast<const uint2*>(&hml[s + hoffl]);
            am4 = fma4h(wmA, uM, am4); al4 = fma4h(wlA, uL, al4);
        }
#pragma unroll
        for (int off = 16; off <= 32; off <<= 1) {
            am4.x += __shfl_xor(am4.x, off); am4.y += __shfl_xor(am4.y, off);
            am4.z += __shfl_xor(am4.z, off); am4.w += __shfl_xor(am4.w, off);
            al4.x += __shfl_xor(al4.x, off); al4.y += __shfl_xor(al4.y, off);
            al4.z += __shfl_xor(al4.z, off); al4.w += __shfl_xor(al4.w, off);
        }
        if (lane < 16) {
            float invm = 1.f / (sm + 1e-16f);
            float invl = 1.f / (sl + 1e-16f);
            float4 rm, rl;
            rm.x = am4.x * invm; rm.y = am4.y * invm; rm.z = am4.z * invm; rm.w = am4.w * invm;
            rl.x = al4.x * invl; rl.y = al4.y * invl; rl.z = al4.z * invl; rl.w = al4.w * invl;
            *reinterpret_cast<float4*>(&red[head][l16 * 4]) = rm;
            *reinterpret_cast<float4*>(&red[3 + head][l16 * 4]) = rl;
        }
    } else {  // streaming fallback (not hit; correctness-safe)
        for (int pass = 0; pass < 2; ++pass) {
            const float* as = pass ? alls : alms;
            float ad = pass ? adl : adm;
            int coff = pass ? 192 : 0;
            float m = -1e30f;
            for (int j = start + lane; j < start + deg; j += 64) {
                float a = as[csr_src[j] * 3 + head] + ad;
                a = a > 0.f ? a : 0.2f * a;
                m = fmaxf(m, a);
            }
#pragma unroll
            for (int off = 32; off; off >>= 1) m = fmaxf(m, __shfl_xor(m, off));
            float acc = 0.f, ssum = 0.f;
            for (int j = start; j < start + deg; ++j) {
                int s = csr_src[j];
                float a = as[s * 3 + head] + ad;
                a = a > 0.f ? a : 0.2f * a;
                float w = __expf(a - m);
                ssum += w;
                acc = fmaf(w, __half2float(hml[(size_t)s * MLW + coff + head * CDIM + lane]), acc);
            }
            red[pass * 3 + head][lane] = acc / (ssum + 1e-16f);
        }
    }
    __syncthreads();
    if (threadIdx.x < 64) {
        out[(size_t)n * CDIM + lane] =
            (red[0][lane] + red[1][lane] + red[2][lane]) * (1.f / 3.f) + b_mu[lane];
    } else if (threadIdx.x < 128) {
        out[(size_t)NN * CDIM + (size_t)n * CDIM + lane] =
            (red[3][lane] + red[4][lane] + red[5][lane]) * (1.f / 3.f) + b_lv[lane];
    }
}

// ---------------------------------------------------------------------------
extern "C" void kernel_launch(void* const* d_in, const int* in_sizes, int n_in,
                              void* d_out, int out_size, void* d_ws, size_t ws_size,
                              hipStream_t stream) {
    const float* x    = (const float*)d_in[0];
    const int*   ei   = (const int*)d_in[1];
    const float* W1   = (const float*)d_in[2];
    const float* a1s  = (const float*)d_in[3];
    const float* a1d  = (const float*)d_in[4];
    const float* b1   = (const float*)d_in[5];
    const float* Wmu  = (const float*)d_in[6];
    const float* amus = (const float*)d_in[7];
    const float* amud = (const float*)d_in[8];
    const float* bmu  = (const float*)d_in[9];
    const float* Wlv  = (const float*)d_in[10];
    const float* alvs = (const float*)d_in[11];
    const float* alvd = (const float*)d_in[12];
    const float* blv  = (const float*)d_in[13];
    float* out = (float*)d_out;

    // workspace carve (256B aligned)
    size_t off = 0;
    auto carve = [&](size_t bytes) {
        void* p = (char*)d_ws + off;
        off += (bytes + 255) & ~(size_t)255;
        return p;
    };
    int*    cnt      = (int*)carve((size_t)NN * 4);
    int*    row_ptr  = (int*)carve((size_t)(NN + 1) * 4);
    int*    scanaux  = (int*)carve(64 * 4);
    int*    csr      = (int*)carve((size_t)ET * 4);
    __half* h1f16    = (__half*)carve((size_t)NN * HC * 2);
    __half* hml      = (__half*)carve((size_t)NN * MLW * 2);
    unsigned short* w1h  = (unsigned short*)carve((size_t)HC * FIN * 2);
    unsigned short* w1l  = (unsigned short*)carve((size_t)HC * FIN * 2);
    unsigned short* wmlh = (unsigned short*)carve((size_t)MLW * HC * 2);
    unsigned short* wmll = (unsigned short*)carve((size_t)MLW * HC * 2);
    unsigned short* hrh  = (unsigned short*)carve((size_t)NN * HC * 2);
    unsigned short* hrl  = (unsigned short*)carve((size_t)NN * HC * 2);
    float*  al1s     = (float*)carve((size_t)NN * 3 * 4);
    float*  al1d     = (float*)carve((size_t)NN * 3 * 4);
    float*  alms     = (float*)carve((size_t)NN * 3 * 4);
    float*  almd     = (float*)carve((size_t)NN * 3 * 4);
    float*  alls     = (float*)carve((size_t)NN * 3 * 4);
    float*  alld     = (float*)carve((size_t)NN * 3 * 4);

    // ---- 1: weight splits + zero cnt/scanaux ----
    split_w_kernel<<<120 + (NN + 255) / 256, 256, 0, stream>>>(
        W1, Wmu, Wlv, w1h, w1l, wmlh, wmll, cnt, scanaux);

    // ---- 2-4: CSR build ----
    hist_kernel<<<(ET + 255) / 256, 256, 0, stream>>>(ei, cnt);
    scan_fused_kernel<<<(NN + SCAN_BLK - 1) / SCAN_BLK, SCAN_BLK, 0, stream>>>(
        cnt, row_ptr, scanaux);
    scatter_kernel<<<(ET + 255) / 256, 256, 0, stream>>>(ei, cnt, row_ptr, csr);

    // ---- 5-6: layer 1 (GEMM + fused al, then aggregation) ----
    dim3 g1((NN + 127) / 128, NHEAD);
    sgemm1<<<g1, 256, 0, stream>>>(x, w1h, w1l, h1f16, a1s, a1d, al1s, al1d);
    agg_cat_kernel<<<NN, 192, 0, stream>>>(row_ptr, csr, h1f16, al1s, al1d, b1, hrh, hrl);

    // ---- 7-8: mu/lv (fused GEMM + fused al, then aggregation) ----
    dim3 g2((NN + 127) / 128, 2 * NHEAD);
    sgemm23<<<g2, 256, 0, stream>>>(hrh, hrl, wmlh, wmll, hml,
                                    amus, amud, alvs, alvd,
                                    alms, almd, alls, alld);
    agg_mean2_kernel<<<NN, 192, 0, stream>>>(row_ptr, csr, hml,
                                             alms, almd, alls, alld, bmu, blv, out);
}